// Round 3
// baseline (912.703 us; speedup 1.0000x reference)
//
#include <hip/hip_runtime.h>

#define NTOK 16384
#define DMODEL 1024
#define DHID 4096
#define NEXP 8
#define CAP 512

typedef __attribute__((ext_vector_type(8))) short bfrag_t;
typedef __attribute__((ext_vector_type(4))) float ffrag_t;

__device__ __forceinline__ unsigned short f2bf(float f) {
  unsigned u = __float_as_uint(f);
  u += 0x7FFFu + ((u >> 16) & 1u);
  return (unsigned short)(u >> 16);
}

__device__ __forceinline__ float gelu_tanh(float x) {
  return 0.5f * x * (1.0f + tanhf(0.7978845608028654f * (x + 0.044715f * x * x * x)));
}

// ---------------- convert f32 -> bf16 flat ----------------
__global__ void k_convert_bf16(const float* __restrict__ in, unsigned short* __restrict__ out, int n4) {
  int i = blockIdx.x * blockDim.x + threadIdx.x;
  int stride = gridDim.x * blockDim.x;
  for (; i < n4; i += stride) {
    float4 v = ((const float4*)in)[i];
    ushort4 o;
    o.x = f2bf(v.x); o.y = f2bf(v.y); o.z = f2bf(v.z); o.w = f2bf(v.w);
    ((ushort4*)out)[i] = o;
  }
}

// ------------- transpose+convert: in [K,N] f32 -> out [N,K] bf16, batch z -------------
__global__ void k_trans_conv(const float* __restrict__ in, unsigned short* __restrict__ out, int K, int N) {
  const size_t zb = blockIdx.z;
  in  += zb * (size_t)K * N;
  out += zb * (size_t)N * K;
  __shared__ float tile[32][33];
  const int n0 = blockIdx.x * 32, k0 = blockIdx.y * 32;
  const int tx = threadIdx.x & 31, ty = threadIdx.x >> 5;
#pragma unroll
  for (int i = 0; i < 4; ++i) {
    int k = ty + i * 8;
    tile[k][tx] = in[(size_t)(k0 + k) * N + n0 + tx];
  }
  __syncthreads();
#pragma unroll
  for (int i = 0; i < 4; ++i) {
    int n = ty + i * 8;
    out[(size_t)(n0 + n) * K + k0 + tx] = f2bf(tile[tx][n]);
  }
}

// ---------------- router: probs[e][t] ----------------
__global__ __launch_bounds__(256) void k_router(const float* __restrict__ x, const float* __restrict__ gw,
                                                const float* __restrict__ gb, const float* __restrict__ temp,
                                                float* __restrict__ probs) {
  __shared__ float gws[DMODEL * NEXP];
  for (int i = threadIdx.x; i < DMODEL * NEXP; i += 256) gws[i] = gw[i];
  __syncthreads();
  const int wave = threadIdx.x >> 6, lane = threadIdx.x & 63;
  const int t = blockIdx.x * 4 + wave;
  const float* xr = x + (size_t)t * DMODEL;
  float acc[NEXP];
#pragma unroll
  for (int e = 0; e < NEXP; ++e) acc[e] = 0.f;
  for (int d = lane; d < DMODEL; d += 64) {
    float xv = xr[d];
#pragma unroll
    for (int e = 0; e < NEXP; ++e) acc[e] += xv * gws[d * NEXP + e];
  }
#pragma unroll
  for (int off = 32; off >= 1; off >>= 1) {
#pragma unroll
    for (int e = 0; e < NEXP; ++e) acc[e] += __shfl_xor(acc[e], off);
  }
  if (lane == 0) {
    float st = fmaxf(temp[0], 0.1f);
    float m = -1e30f;
#pragma unroll
    for (int e = 0; e < NEXP; ++e) { acc[e] = (acc[e] + gb[e]) / st; m = fmaxf(m, acc[e]); }
    float s = 0.f;
#pragma unroll
    for (int e = 0; e < NEXP; ++e) { acc[e] = expf(acc[e] - m); s += acc[e]; }
    float inv = 1.f / s;
#pragma unroll
    for (int e = 0; e < NEXP; ++e) probs[(size_t)e * NTOK + t] = acc[e] * inv;
  }
}

// ---------------- exact top-512 per expert (radix select, tie -> lowest index) ----------------
__global__ __launch_bounds__(256) void k_topk(const float* __restrict__ probs, int* __restrict__ tok,
                                              float* __restrict__ scores, int* __restrict__ eqbuf) {
  const int e = blockIdx.x;
  const float* p = probs + (size_t)e * NTOK;
  int* eq = eqbuf + (size_t)e * NTOK;
  __shared__ int hist[256];
  __shared__ unsigned sh_pref;
  __shared__ int sh_k, sh_gt, sh_eq, sh_cnt;
  const int tid = threadIdx.x;
  if (tid == 0) { sh_pref = 0u; sh_k = CAP; }
  __syncthreads();
  for (int pass = 3; pass >= 0; --pass) {
    hist[tid] = 0;
    __syncthreads();
    const unsigned pref = sh_pref;
    const int shift = pass * 8;
    for (int t = tid; t < NTOK; t += 256) {
      unsigned key = __float_as_uint(p[t]);
      bool cand = (pass == 3) || ((key >> (shift + 8)) == pref);
      if (cand) atomicAdd(&hist[(key >> shift) & 255], 1);
    }
    __syncthreads();
    if (tid == 0) {
      int k = sh_k;
      int d = 255;
      while (hist[d] < k) { k -= hist[d]; --d; }
      sh_k = k;
      sh_pref = (pref << 8) | (unsigned)d;
    }
    __syncthreads();
  }
  const unsigned Kstar = sh_pref;
  const int need_eq = sh_k;
  if (tid == 0) { sh_gt = 0; sh_eq = 0; }
  __syncthreads();
  for (int t = tid; t < NTOK; t += 256) {
    unsigned key = __float_as_uint(p[t]);
    if (key > Kstar) {
      int pos = atomicAdd(&sh_gt, 1);
      tok[e * CAP + pos] = t;
      scores[e * CAP + pos] = p[t];
    } else if (key == Kstar) {
      int q = atomicAdd(&sh_eq, 1);
      eq[q] = t;
    }
  }
  __syncthreads();
  const int cg = sh_gt, ce = sh_eq;
  if (ce <= need_eq) {
    for (int j = tid; j < ce; j += 256) {
      tok[e * CAP + cg + j] = eq[j];
      scores[e * CAP + cg + j] = p[eq[j]];
    }
  } else {
    int lo = 0, hi = NTOK - 1;
    while (lo < hi) {
      int mid = (lo + hi) >> 1;
      if (tid == 0) sh_cnt = 0;
      __syncthreads();
      for (int j = tid; j < ce; j += 256)
        if (eq[j] <= mid) atomicAdd(&sh_cnt, 1);
      __syncthreads();
      if (sh_cnt >= need_eq) hi = mid; else lo = mid + 1;
      __syncthreads();
    }
    if (tid == 0) sh_cnt = 0;
    __syncthreads();
    for (int j = tid; j < ce; j += 256) {
      if (eq[j] <= lo) {
        int pos = cg + atomicAdd(&sh_cnt, 1);
        tok[e * CAP + pos] = eq[j];
        scores[e * CAP + pos] = p[eq[j]];
      }
    }
  }
}

// ---------------- gather selected tokens (bf16 rows) ----------------
__global__ void k_gather(const unsigned short* __restrict__ xb, const int* __restrict__ tok,
                         unsigned short* __restrict__ atok) {
  const int row = blockIdx.x;
  const int t = tok[row];
  const uint2* src = (const uint2*)(xb + (size_t)t * DMODEL);
  uint2* dst = (uint2*)(atok + (size_t)row * DMODEL);
  dst[threadIdx.x] = src[threadIdx.x];
}

// =====================================================================================
// 256x256 tile, BK=64, 8 waves (2M x 4N), 2 LDS dbuf of 64KB, 4-phase-per-K-tile
// interleave with counted vmcnt (T3+T4), planar K-granule LDS layout (conflict-free
// ds_read_b128 + linear gload_lds dest), inline-asm ds_reads (opaque to compiler =>
// no auto vmcnt(0)), setprio around MFMA clusters (T5), slab XCD swizzle (T1).
//
// LDS map per buf b (65536B): Ak0 @0, Ak1 @16384, Bk0 @32768, Bk1 @49152.
// Granule = 256 rows x 32 cols bf16 stored planar: addr = p*4096 + row*16,
//   p = k-subgranule (8 bf16), row = M/N row. gload_lds writes it LINEARLY
//   (slot = p*256+row), source address pre-permuted per lane.
// Phases per K-tile t (buf c = t&1, staging tile t+1 into buf n = c^1):
//   p0: dsr A(kk0)x8 + B(kk0,ni01)x2 | stage Ak0(t+1) |          bar | mfma kk0 ni01 | bar
//   p1: dsr B(kk0,ni23)x2            | stage Bk0(t+1) | vmcnt(4) bar | mfma kk0 ni23 | bar
//   p2: dsr A(kk1)x8 + B(kk1,ni01)x2 | stage Ak1(t+1) |          bar | mfma kk1 ni01 | bar
//   p3: dsr B(kk1,ni23)x2            | stage Bk1(t+1) | vmcnt(4) bar | mfma kk1 ni23 | bar
// vmcnt(4)=2 stages outstanding => consumed granule was staged >=2 stages earlier:
//   Ak0/Bk0(t) staged t-1.p0/p1, forced by t-1.p3's vmcnt(4); Ak1/Bk1(t) staged
//   t-1.p2/p3, forced by t.p1's vmcnt(4) before their reads at t.p2/p3.  Race-free.
// =====================================================================================

#define DSR(dst, addr, OFFL) \
  asm volatile("ds_read_b128 %0, %1 offset:" OFFL : "=v"(dst) : "v"(addr))

#define STG(SRC, TT, KKs, REGB)                                                              \
  do {                                                                                       \
    _Pragma("unroll") for (int _i = 0; _i < 2; ++_i) {                                       \
      __builtin_amdgcn_global_load_lds(                                                      \
          (const __attribute__((address_space(1))) unsigned int*)(SRC[_i] +                  \
              (size_t)(TT) * 64 + (KKs) * 32),                                               \
          (__attribute__((address_space(3))) unsigned int*)(lds + (REGB) + dstOff[_i]),      \
          16, 0, 0);                                                                         \
    }                                                                                        \
  } while (0)

#define RD_A8(OFFL)                                                     \
  DSR(af[0], adrA0, OFFL); DSR(af[1], adrA1, OFFL);                     \
  DSR(af[2], adrA2, OFFL); DSR(af[3], adrA3, OFFL);                     \
  DSR(af[4], adrA4, OFFL); DSR(af[5], adrA5, OFFL);                     \
  DSR(af[6], adrA6, OFFL); DSR(af[7], adrA7, OFFL)

#define MFMA16(J0, J1)                                                                        \
  _Pragma("unroll") for (int _m = 0; _m < 8; ++_m) {                                         \
    acc[_m][J0] = __builtin_amdgcn_mfma_f32_16x16x32_bf16(af[_m], bf[0], acc[_m][J0], 0, 0, 0); \
    acc[_m][J1] = __builtin_amdgcn_mfma_f32_16x16x32_bf16(af[_m], bf[1], acc[_m][J1], 0, 0, 0); \
  }

#define PH_TAIL(J0, J1)                                    \
  asm volatile("s_waitcnt lgkmcnt(0)" ::: "memory");       \
  __builtin_amdgcn_sched_barrier(0);                       \
  __builtin_amdgcn_s_setprio(1);                           \
  MFMA16(J0, J1);                                          \
  __builtin_amdgcn_s_setprio(0);                           \
  __builtin_amdgcn_sched_barrier(0);                       \
  __builtin_amdgcn_s_barrier()

// MODE 0: outB[(zb*M+m)*N+n] = bf16(gelu(v))   MODE 1: outF[m*N+n] = v
template <int MODE>
__global__ __launch_bounds__(512, 2) void k_gemm_big(
    const unsigned short* __restrict__ A, const unsigned short* __restrict__ Bt,
    const float* __restrict__ bias, float* __restrict__ outF, unsigned short* __restrict__ outB,
    int M, int N, int K) {
  const int zb = blockIdx.z;
  A += (size_t)zb * M * K;
  Bt += (size_t)zb * N * K;
  const float* bz = bias + (size_t)zb * N;

  // T1: slab XCD swizzle. 32 concurrent blocks per XCD share 8 A-panels + <=4 B-panels.
  const int gx = gridDim.x, gy = gridDim.y;
  const int nwg = gx * gy;
  const int id = blockIdx.x + blockIdx.y * gx;
  int bx, by;
  if ((gx & 7) == 0) {
    const int x = id & 7, c = id >> 3, H = gx >> 3;
    bx = x * H + (c % H);
    by = c / H;
  } else {
    const int q = nwg >> 3;
    const int sw = (id & 7) * q + (id >> 3);
    bx = sw % gx;
    by = sw / gx;
  }
  const int m0 = bx * 256, n0 = by * 256;

  const int tid = threadIdx.x, wave = tid >> 6, lane = tid & 63;
  const int wm = (wave >> 2) * 128;  // wave's A-row base
  const int wn = (wave & 3) * 64;    // wave's B-row base

  __shared__ alignas(16) char lds[131072];

  ffrag_t acc[8][4];
#pragma unroll
  for (int i = 0; i < 8; ++i)
#pragma unroll
    for (int j = 0; j < 4; ++j)
#pragma unroll
      for (int r = 0; r < 4; ++r) acc[i][j][r] = 0.f;

  // staging source (planar pre-permutation) + wave-uniform LDS dest offsets
  const unsigned short* gsrcA[2];
  const unsigned short* gsrcB[2];
  unsigned dstOff[2];
#pragma unroll
  for (int i = 0; i < 2; ++i) {
    const int s = i * 512 + tid;
    const int row = s & 255, p = s >> 8;
    gsrcA[i] = A + (size_t)(m0 + row) * K + p * 8;
    gsrcB[i] = Bt + (size_t)(n0 + row) * K + p * 8;
    dstOff[i] = (unsigned)((i * 512 + wave * 64) * 16);
  }

  // ds_read byte offsets (buf0 base); kk handled by immediate offset (0 / 16384)
  int aoff[8], boff[4];
#pragma unroll
  for (int mi = 0; mi < 8; ++mi)
    aoff[mi] = ((lane >> 4) << 12) + (wm + mi * 16 + (lane & 15)) * 16;
#pragma unroll
  for (int ni = 0; ni < 4; ++ni)
    boff[ni] = 32768 + ((lane >> 4) << 12) + (wn + ni * 16 + (lane & 15)) * 16;

  const int NT = K >> 6;

  // prologue: stage all 4 granules of tile 0 into buf0; force Ak0,Bk0 (vmcnt(4))
  STG(gsrcA, 0, 0, 0);
  STG(gsrcB, 0, 0, 32768);
  STG(gsrcA, 0, 1, 16384);
  STG(gsrcB, 0, 1, 49152);
  asm volatile("s_waitcnt vmcnt(4)" ::: "memory");
  __builtin_amdgcn_s_barrier();

  bfrag_t af[8], bf[2];

  for (int t = 0; t < NT; ++t) {
    const int bc = (t & 1) << 16;
    const int bn = bc ^ 65536;
    const int tn = (t + 1 == NT) ? 0 : t + 1;  // dummy wrap keeps vmcnt bookkeeping uniform

    const int adrA0 = aoff[0] + bc, adrA1 = aoff[1] + bc, adrA2 = aoff[2] + bc,
              adrA3 = aoff[3] + bc, adrA4 = aoff[4] + bc, adrA5 = aoff[5] + bc,
              adrA6 = aoff[6] + bc, adrA7 = aoff[7] + bc;
    const int adrB0 = boff[0] + bc, adrB1 = boff[1] + bc, adrB2 = boff[2] + bc,
              adrB3 = boff[3] + bc;

    // ---- phase 0 ----
    RD_A8("0");
    DSR(bf[0], adrB0, "0");
    DSR(bf[1], adrB1, "0");
    STG(gsrcA, tn, 0, bn);
    __builtin_amdgcn_s_barrier();
    PH_TAIL(0, 1);

    // ---- phase 1 ----
    DSR(bf[0], adrB2, "0");
    DSR(bf[1], adrB3, "0");
    STG(gsrcB, tn, 0, bn + 32768);
    asm volatile("s_waitcnt vmcnt(4)" ::: "memory");
    __builtin_amdgcn_s_barrier();
    PH_TAIL(2, 3);

    // ---- phase 2 ----
    RD_A8("16384");
    DSR(bf[0], adrB0, "16384");
    DSR(bf[1], adrB1, "16384");
    STG(gsrcA, tn, 1, bn + 16384);
    __builtin_amdgcn_s_barrier();
    PH_TAIL(0, 1);

    // ---- phase 3 ----
    DSR(bf[0], adrB2, "16384");
    DSR(bf[1], adrB3, "16384");
    STG(gsrcB, tn, 1, bn + 49152);
    asm volatile("s_waitcnt vmcnt(4)" ::: "memory");
    __builtin_amdgcn_s_barrier();
    PH_TAIL(2, 3);
  }

  // drain dummy stages before reusing LDS as epilogue scratch
  asm volatile("s_waitcnt vmcnt(0)" ::: "memory");
  __builtin_amdgcn_s_barrier();

  const int rq = lane >> 4, cs = lane & 15;
  if (MODE == 0) {
    // LDS-bounce epilogue: full 128B-line bf16 stores (kills partial-line RMW).
    float bv[4];
#pragma unroll
    for (int ni = 0; ni < 4; ++ni) bv[ni] = bz[n0 + wn + ni * 16 + cs];
    unsigned short* wbase = (unsigned short*)(lds + wave * 2304);
#pragma unroll
    for (int mi = 0; mi < 8; ++mi) {
#pragma unroll
      for (int ni = 0; ni < 4; ++ni)
#pragma unroll
        for (int r = 0; r < 4; ++r) {
          float v = acc[mi][ni][r] + bv[ni];
          wbase[(rq * 4 + r) * 72 + ni * 16 + cs] = f2bf(gelu_tanh(v));
        }
      // read back 16B/lane, rows lane>>3 and (lane>>3)+8
      const int rrow = lane >> 3, uu = lane & 7;
      uint4 v0 = *(const uint4*)((const char*)wbase + rrow * 144 + uu * 16);
      uint4 v1 = *(const uint4*)((const char*)wbase + (rrow + 8) * 144 + uu * 16);
      unsigned short* orow0 =
          outB + ((size_t)zb * M + m0 + wm + mi * 16 + rrow) * N + n0 + wn + uu * 8;
      unsigned short* orow1 =
          outB + ((size_t)zb * M + m0 + wm + mi * 16 + rrow + 8) * N + n0 + wn + uu * 8;
      *(uint4*)orow0 = v0;
      *(uint4*)orow1 = v1;
    }
  } else {
#pragma unroll
    for (int ni = 0; ni < 4; ++ni) {
      const int n = n0 + wn + ni * 16 + cs;
      const float bv = bz[n];
#pragma unroll
      for (int mi = 0; mi < 8; ++mi)
#pragma unroll
        for (int r = 0; r < 4; ++r) {
          const int m = m0 + wm + mi * 16 + rq * 4 + r;
          outF[(size_t)m * N + n] = acc[mi][ni][r] + bv;
        }
    }
  }
}

// ---------------- 128x128 kernel for the expert-2 scatter GEMM ----------------
__global__ __launch_bounds__(256) void k_gemm_scatter(
    const unsigned short* __restrict__ A, const unsigned short* __restrict__ Bt,
    const float* __restrict__ bias, float* __restrict__ outF,
    const int* __restrict__ tok, const float* __restrict__ scale, int M, int N, int K) {
  const int zb = blockIdx.z;
  A += (size_t)zb * M * K;
  Bt += (size_t)zb * N * K;
  const float* bz = bias + (size_t)zb * N;

  const int m0 = blockIdx.x * 128, n0 = blockIdx.y * 128;
  const int tid = threadIdx.x, wave = tid >> 6, lane = tid & 63;
  const int wm = (wave >> 1) * 64, wn = (wave & 1) * 64;

  __shared__ unsigned short As[128 * 64];
  __shared__ unsigned short Bs[128 * 64];

  ffrag_t acc[4][4];
#pragma unroll
  for (int i = 0; i < 4; ++i)
#pragma unroll
    for (int j = 0; j < 4; ++j)
#pragma unroll
      for (int r = 0; r < 4; ++r) acc[i][j][r] = 0.f;

  int rr[4], gg[4], lb[4];
#pragma unroll
  for (int it = 0; it < 4; ++it) {
    int L = it * 256 + wave * 64 + lane;
    rr[it] = L >> 3;
    gg[it] = (L & 7) ^ (rr[it] & 7);
    lb[it] = (it * 256 + wave * 64) * 16;
  }

  for (int kt = 0; kt < K; kt += 64) {
#pragma unroll
    for (int it = 0; it < 4; ++it) {
      const unsigned short* sA = A + (size_t)(m0 + rr[it]) * K + kt + gg[it] * 8;
      const unsigned short* sB = Bt + (size_t)(n0 + rr[it]) * K + kt + gg[it] * 8;
      __builtin_amdgcn_global_load_lds((const __attribute__((address_space(1))) unsigned int*)sA,
                                       (__attribute__((address_space(3))) unsigned int*)((char*)As + lb[it]),
                                       16, 0, 0);
      __builtin_amdgcn_global_load_lds((const __attribute__((address_space(1))) unsigned int*)sB,
                                       (__attribute__((address_space(3))) unsigned int*)((char*)Bs + lb[it]),
                                       16, 0, 0);
    }
    __syncthreads();
#pragma unroll
    for (int kk = 0; kk < 2; ++kk) {
      bfrag_t af2[4], bf2[4];
      const int gl = kk * 4 + (lane >> 4);
#pragma unroll
      for (int mi = 0; mi < 4; ++mi) {
        int r = wm + mi * 16 + (lane & 15);
        af2[mi] = *(const bfrag_t*)&As[r * 64 + ((gl ^ (r & 7)) * 8)];
      }
#pragma unroll
      for (int ni = 0; ni < 4; ++ni) {
        int r = wn + ni * 16 + (lane & 15);
        bf2[ni] = *(const bfrag_t*)&Bs[r * 64 + ((gl ^ (r & 7)) * 8)];
      }
#pragma unroll
      for (int mi = 0; mi < 4; ++mi)
#pragma unroll
        for (int ni = 0; ni < 4; ++ni)
          acc[mi][ni] = __builtin_amdgcn_mfma_f32_16x16x32_bf16(af2[mi], bf2[ni], acc[mi][ni], 0, 0, 0);
    }
    __syncthreads();
  }

  const int rsub = (lane >> 4) * 4, csub = lane & 15;
#pragma unroll
  for (int ni = 0; ni < 4; ++ni) {
    const int n = n0 + wn + ni * 16 + csub;
    const float bv = bz[n];
#pragma unroll
    for (int mi = 0; mi < 4; ++mi) {
#pragma unroll
      for (int r = 0; r < 4; ++r) {
        const int m = m0 + wm + mi * 16 + rsub + r;
        float v = acc[mi][ni][r] + bv;
        const int t = tok[zb * M + m];
        const float s = scale[zb * M + m];
        atomicAdd(&outF[(size_t)t * N + n], v * s);
      }
    }
  }
}

extern "C" void kernel_launch(void* const* d_in, const int* in_sizes, int n_in,
                              void* d_out, int out_size, void* d_ws, size_t ws_size,
                              hipStream_t stream) {
  const float* x      = (const float*)d_in[0];
  const float* gate_w = (const float*)d_in[1];
  const float* gate_b = (const float*)d_in[2];
  const float* temp   = (const float*)d_in[3];
  const float* sw1    = (const float*)d_in[4];
  const float* sb1    = (const float*)d_in[5];
  const float* sw2    = (const float*)d_in[6];
  const float* sb2    = (const float*)d_in[7];
  const float* ew1    = (const float*)d_in[8];
  const float* eb1    = (const float*)d_in[9];
  const float* ew2    = (const float*)d_in[10];
  const float* eb2    = (const float*)d_in[11];
  float* out = (float*)d_out;

  char* ws = (char*)d_ws;
  size_t o = 0;
  auto take = [&](size_t bytes) { char* p = ws + o; o += (bytes + 255) & ~(size_t)255; return p; };
  unsigned short* x_bf = (unsigned short*)take((size_t)NTOK * DMODEL * 2);
  unsigned short* w1t  = (unsigned short*)take((size_t)DMODEL * DHID * 2);
  unsigned short* w2t  = (unsigned short*)take((size_t)DHID * DMODEL * 2);
  unsigned short* ew1t = (unsigned short*)take((size_t)NEXP * DMODEL * DHID * 2);
  unsigned short* ew2t = (unsigned short*)take((size_t)NEXP * DHID * DMODEL * 2);
  float* probs         = (float*)take((size_t)NEXP * NTOK * 4);
  int* tok             = (int*)take((size_t)NEXP * CAP * 4);
  float* scores        = (float*)take((size_t)NEXP * CAP * 4);
  int* eqbuf           = (int*)take((size_t)NEXP * NTOK * 4);
  unsigned short* atok = (unsigned short*)take((size_t)NEXP * CAP * DMODEL * 2);
  unsigned short* he   = (unsigned short*)take((size_t)NEXP * CAP * DHID * 2);
  unsigned short* hs   = (unsigned short*)take((size_t)NTOK * DHID * 2);

  // prep: bf16 conversions + weight transposes
  k_convert_bf16<<<4096, 256, 0, stream>>>(x, x_bf, NTOK * DMODEL / 4);
  k_trans_conv<<<dim3(DHID / 32, DMODEL / 32, 1), 256, 0, stream>>>(sw1, w1t, DMODEL, DHID);
  k_trans_conv<<<dim3(DMODEL / 32, DHID / 32, 1), 256, 0, stream>>>(sw2, w2t, DHID, DMODEL);
  k_trans_conv<<<dim3(DHID / 32, DMODEL / 32, NEXP), 256, 0, stream>>>(ew1, ew1t, DMODEL, DHID);
  k_trans_conv<<<dim3(DMODEL / 32, DHID / 32, NEXP), 256, 0, stream>>>(ew2, ew2t, DHID, DMODEL);

  // router + top-k + gather
  k_router<<<NTOK / 4, 256, 0, stream>>>(x, gate_w, gate_b, temp, probs);
  k_topk<<<NEXP, 256, 0, stream>>>(probs, tok, scores, eqbuf);
  k_gather<<<NEXP * CAP, 256, 0, stream>>>(x_bf, tok, atok);

  // shared FFN (256^2 4-phase pipelined kernel)
  k_gemm_big<0><<<dim3(NTOK / 256, DHID / 256, 1), 512, 0, stream>>>(
      x_bf, w1t, sb1, nullptr, hs, NTOK, DHID, DMODEL);
  k_gemm_big<1><<<dim3(NTOK / 256, DMODEL / 256, 1), 512, 0, stream>>>(
      hs, w2t, sb2, out, nullptr, NTOK, DMODEL, DHID);

  // routed experts: FFN-1 on the big kernel; FFN-2 scatter on 128^2 (256 blocks)
  k_gemm_big<0><<<dim3(CAP / 256, DHID / 256, NEXP), 512, 0, stream>>>(
      atok, ew1t, eb1, nullptr, he, CAP, DHID, DMODEL);
  k_gemm_scatter<<<dim3(CAP / 128, DMODEL / 128, NEXP), 256, 0, stream>>>(
      he, ew2t, eb2, out, tok, scores, CAP, DMODEL, DHID);
}

// Round 4
// 906.720 us; speedup vs baseline: 1.0066x; 1.0066x over previous
//
#include <hip/hip_runtime.h>

#define NTOK 16384
#define DMODEL 1024
#define DHID 4096
#define NEXP 8
#define CAP 512

typedef __attribute__((ext_vector_type(8))) short bfrag_t;
typedef __attribute__((ext_vector_type(4))) float ffrag_t;

__device__ __forceinline__ unsigned short f2bf(float f) {
  unsigned u = __float_as_uint(f);
  u += 0x7FFFu + ((u >> 16) & 1u);
  return (unsigned short)(u >> 16);
}

__device__ __forceinline__ float gelu_tanh(float x) {
  return 0.5f * x * (1.0f + tanhf(0.7978845608028654f * (x + 0.044715f * x * x * x)));
}

// ---------------- convert f32 -> bf16 flat ----------------
__global__ void k_convert_bf16(const float* __restrict__ in, unsigned short* __restrict__ out, int n4) {
  int i = blockIdx.x * blockDim.x + threadIdx.x;
  int stride = gridDim.x * blockDim.x;
  for (; i < n4; i += stride) {
    float4 v = ((const float4*)in)[i];
    ushort4 o;
    o.x = f2bf(v.x); o.y = f2bf(v.y); o.z = f2bf(v.z); o.w = f2bf(v.w);
    ((ushort4*)out)[i] = o;
  }
}

// ------------- transpose+convert: in [K,N] f32 -> out [N,K] bf16, batch z -------------
__global__ void k_trans_conv(const float* __restrict__ in, unsigned short* __restrict__ out, int K, int N) {
  const size_t zb = blockIdx.z;
  in  += zb * (size_t)K * N;
  out += zb * (size_t)N * K;
  __shared__ float tile[32][33];
  const int n0 = blockIdx.x * 32, k0 = blockIdx.y * 32;
  const int tx = threadIdx.x & 31, ty = threadIdx.x >> 5;
#pragma unroll
  for (int i = 0; i < 4; ++i) {
    int k = ty + i * 8;
    tile[k][tx] = in[(size_t)(k0 + k) * N + n0 + tx];
  }
  __syncthreads();
#pragma unroll
  for (int i = 0; i < 4; ++i) {
    int n = ty + i * 8;
    out[(size_t)(n0 + n) * K + k0 + tx] = f2bf(tile[tx][n]);
  }
}

// ---------------- router: probs[e][t] ----------------
__global__ __launch_bounds__(256) void k_router(const float* __restrict__ x, const float* __restrict__ gw,
                                                const float* __restrict__ gb, const float* __restrict__ temp,
                                                float* __restrict__ probs) {
  __shared__ float gws[DMODEL * NEXP];
  for (int i = threadIdx.x; i < DMODEL * NEXP; i += 256) gws[i] = gw[i];
  __syncthreads();
  const int wave = threadIdx.x >> 6, lane = threadIdx.x & 63;
  const int t = blockIdx.x * 4 + wave;
  const float* xr = x + (size_t)t * DMODEL;
  float acc[NEXP];
#pragma unroll
  for (int e = 0; e < NEXP; ++e) acc[e] = 0.f;
  for (int d = lane; d < DMODEL; d += 64) {
    float xv = xr[d];
#pragma unroll
    for (int e = 0; e < NEXP; ++e) acc[e] += xv * gws[d * NEXP + e];
  }
#pragma unroll
  for (int off = 32; off >= 1; off >>= 1) {
#pragma unroll
    for (int e = 0; e < NEXP; ++e) acc[e] += __shfl_xor(acc[e], off);
  }
  if (lane == 0) {
    float st = fmaxf(temp[0], 0.1f);
    float m = -1e30f;
#pragma unroll
    for (int e = 0; e < NEXP; ++e) { acc[e] = (acc[e] + gb[e]) / st; m = fmaxf(m, acc[e]); }
    float s = 0.f;
#pragma unroll
    for (int e = 0; e < NEXP; ++e) { acc[e] = expf(acc[e] - m); s += acc[e]; }
    float inv = 1.f / s;
#pragma unroll
    for (int e = 0; e < NEXP; ++e) probs[(size_t)e * NTOK + t] = acc[e] * inv;
  }
}

// ---------------- exact top-512 per expert (radix select, tie -> lowest index) ----------------
__global__ __launch_bounds__(256) void k_topk(const float* __restrict__ probs, int* __restrict__ tok,
                                              float* __restrict__ scores, int* __restrict__ eqbuf) {
  const int e = blockIdx.x;
  const float* p = probs + (size_t)e * NTOK;
  int* eq = eqbuf + (size_t)e * NTOK;
  __shared__ int hist[256];
  __shared__ unsigned sh_pref;
  __shared__ int sh_k, sh_gt, sh_eq, sh_cnt;
  const int tid = threadIdx.x;
  if (tid == 0) { sh_pref = 0u; sh_k = CAP; }
  __syncthreads();
  for (int pass = 3; pass >= 0; --pass) {
    hist[tid] = 0;
    __syncthreads();
    const unsigned pref = sh_pref;
    const int shift = pass * 8;
    for (int t = tid; t < NTOK; t += 256) {
      unsigned key = __float_as_uint(p[t]);
      bool cand = (pass == 3) || ((key >> (shift + 8)) == pref);
      if (cand) atomicAdd(&hist[(key >> shift) & 255], 1);
    }
    __syncthreads();
    if (tid == 0) {
      int k = sh_k;
      int d = 255;
      while (hist[d] < k) { k -= hist[d]; --d; }
      sh_k = k;
      sh_pref = (pref << 8) | (unsigned)d;
    }
    __syncthreads();
  }
  const unsigned Kstar = sh_pref;
  const int need_eq = sh_k;
  if (tid == 0) { sh_gt = 0; sh_eq = 0; }
  __syncthreads();
  for (int t = tid; t < NTOK; t += 256) {
    unsigned key = __float_as_uint(p[t]);
    if (key > Kstar) {
      int pos = atomicAdd(&sh_gt, 1);
      tok[e * CAP + pos] = t;
      scores[e * CAP + pos] = p[t];
    } else if (key == Kstar) {
      int q = atomicAdd(&sh_eq, 1);
      eq[q] = t;
    }
  }
  __syncthreads();
  const int cg = sh_gt, ce = sh_eq;
  if (ce <= need_eq) {
    for (int j = tid; j < ce; j += 256) {
      tok[e * CAP + cg + j] = eq[j];
      scores[e * CAP + cg + j] = p[eq[j]];
    }
  } else {
    int lo = 0, hi = NTOK - 1;
    while (lo < hi) {
      int mid = (lo + hi) >> 1;
      if (tid == 0) sh_cnt = 0;
      __syncthreads();
      for (int j = tid; j < ce; j += 256)
        if (eq[j] <= mid) atomicAdd(&sh_cnt, 1);
      __syncthreads();
      if (sh_cnt >= need_eq) hi = mid; else lo = mid + 1;
      __syncthreads();
    }
    if (tid == 0) sh_cnt = 0;
    __syncthreads();
    for (int j = tid; j < ce; j += 256) {
      if (eq[j] <= lo) {
        int pos = cg + atomicAdd(&sh_cnt, 1);
        tok[e * CAP + pos] = eq[j];
        scores[e * CAP + pos] = p[eq[j]];
      }
    }
  }
}

// ---------------- gather selected tokens (bf16 rows) ----------------
__global__ void k_gather(const unsigned short* __restrict__ xb, const int* __restrict__ tok,
                         unsigned short* __restrict__ atok) {
  const int row = blockIdx.x;
  const int t = tok[row];
  const uint2* src = (const uint2*)(xb + (size_t)t * DMODEL);
  uint2* dst = (uint2*)(atok + (size_t)row * DMODEL);
  dst[threadIdx.x] = src[threadIdx.x];
}

// =====================================================================================
// 256x256 tile, BK=64, 8 waves (2M x 4N), 2 LDS dbuf of 64KB, 4 phases per K-tile.
// m201-style construction: plain C++ ds_reads (compiler schedules lgkmcnt),
// raw s_barrier, asm counted vmcnt ONLY (no sched_barrier, no asm ds_read),
// setprio around MFMA clusters, planar K-granule LDS (conflict-free b128 reads,
// LINEAR gload_lds dest), slab XCD swizzle, LDS-bounce bf16 epilogue.
//
// LDS per buf (64KB): Ak0 @0, Ak1 @16K, Bk0 @32K, Bk1 @48K. Granule = 256rows x 32cols
// bf16 planar: addr = p*4096 + row*16 (p = 8-elem k-subgranule). gload_lds writes it
// linearly (slot = p*256+row); source address pre-permuted per lane.
// Stage points: p0:Ak0(t+1) p1:Bk0(t+1) p2:Ak1(t+1) p3:Bk1(t+1)  (2 loads each).
// vmcnt(4) at p1-end: forces Ak1(t),Bk1(t) (needed p2/p3); at p3-end: forces
// Ak0(t+1),Bk0(t+1) (needed t+1 p0/p1). vmcnt is issue-ordered => exact. Last tile
// peeled: no stages, vmcnt(0) at p1. Race-free: stages target buf n=c^1 whose last
// reads completed before the barrier ending tile t-1.
// =====================================================================================

#define WAITV4() asm volatile("s_waitcnt vmcnt(4)" ::: "memory")
#define WAITV0() asm volatile("s_waitcnt vmcnt(0)" ::: "memory")
#define BAR()                                  \
  do {                                         \
    asm volatile("" ::: "memory");             \
    __builtin_amdgcn_s_barrier();              \
    asm volatile("" ::: "memory");             \
  } while (0)

#define STG(SRC, TT, KKs, REGB)                                                              \
  do {                                                                                       \
    _Pragma("unroll") for (int _i = 0; _i < 2; ++_i) {                                       \
      __builtin_amdgcn_global_load_lds(                                                      \
          (const __attribute__((address_space(1))) unsigned int*)(SRC[_i] +                  \
              (size_t)(TT) * 64 + (KKs) * 32),                                               \
          (__attribute__((address_space(3))) unsigned int*)(lds + (REGB) + dstOff[_i]),      \
          16, 0, 0);                                                                         \
    }                                                                                        \
  } while (0)

#define LOAD_A(KOFF)                                                          \
  _Pragma("unroll") for (int _mi = 0; _mi < 8; ++_mi)                         \
      af[_mi] = *(const bfrag_t*)(base + aoff[_mi] + (KOFF))

#define LOAD_B2(I0, I1, KOFF)                                                 \
  bf[0] = *(const bfrag_t*)(base + boff[I0] + (KOFF));                        \
  bf[1] = *(const bfrag_t*)(base + boff[I1] + (KOFF))

#define MFMA16(J0, J1)                                                                          \
  _Pragma("unroll") for (int _m = 0; _m < 8; ++_m) {                                            \
    acc[_m][J0] = __builtin_amdgcn_mfma_f32_16x16x32_bf16(af[_m], bf[0], acc[_m][J0], 0, 0, 0); \
    acc[_m][J1] = __builtin_amdgcn_mfma_f32_16x16x32_bf16(af[_m], bf[1], acc[_m][J1], 0, 0, 0); \
  }

#define CLUSTER(J0, J1)                \
  BAR();                               \
  __builtin_amdgcn_s_setprio(1);       \
  MFMA16(J0, J1);                      \
  __builtin_amdgcn_s_setprio(0);       \
  BAR()

// MODE 0: outB[(zb*M+m)*N+n] = bf16(gelu(v))   MODE 1: outF[m*N+n] = v
template <int MODE>
__global__ __launch_bounds__(512, 2) void k_gemm_big(
    const unsigned short* __restrict__ A, const unsigned short* __restrict__ Bt,
    const float* __restrict__ bias, float* __restrict__ outF, unsigned short* __restrict__ outB,
    int M, int N, int K) {
  const int zb = blockIdx.z;
  A += (size_t)zb * M * K;
  Bt += (size_t)zb * N * K;
  const float* bz = bias + (size_t)zb * N;

  // T1: slab XCD swizzle. 32 concurrent blocks/XCD share 8 A-panels + <=4 B-panels.
  const int gx = gridDim.x, gy = gridDim.y;
  const int nwg = gx * gy;
  const int id = blockIdx.x + blockIdx.y * gx;
  int bx, by;
  if ((gx & 7) == 0) {
    const int x = id & 7, c = id >> 3, H = gx >> 3;
    bx = x * H + (c % H);
    by = c / H;
  } else {
    const int q = nwg >> 3;
    const int sw = (id & 7) * q + (id >> 3);
    bx = sw % gx;
    by = sw / gx;
  }
  const int m0 = bx * 256, n0 = by * 256;

  const int tid = threadIdx.x, wave = tid >> 6, lane = tid & 63;
  const int wm = (wave >> 2) * 128;
  const int wn = (wave & 3) * 64;

  __shared__ alignas(16) char lds[131072];

  ffrag_t acc[8][4];
#pragma unroll
  for (int i = 0; i < 8; ++i)
#pragma unroll
    for (int j = 0; j < 4; ++j)
#pragma unroll
      for (int r = 0; r < 4; ++r) acc[i][j][r] = 0.f;

  // staging source (planar pre-permutation) + wave-uniform LDS dest offsets
  const unsigned short* gsrcA[2];
  const unsigned short* gsrcB[2];
  unsigned dstOff[2];
#pragma unroll
  for (int i = 0; i < 2; ++i) {
    const int s = i * 512 + tid;
    const int row = s & 255, p = s >> 8;
    gsrcA[i] = A + (size_t)(m0 + row) * K + p * 8;
    gsrcB[i] = Bt + (size_t)(n0 + row) * K + p * 8;
    dstOff[i] = (unsigned)((i * 512 + wave * 64) * 16);
  }

  // ds_read byte offsets (buf0, kk0); kk1 = +16384, buf1 = +65536
  int aoff[8], boff[4];
#pragma unroll
  for (int mi = 0; mi < 8; ++mi)
    aoff[mi] = ((lane >> 4) << 12) + (wm + mi * 16 + (lane & 15)) * 16;
#pragma unroll
  for (int ni = 0; ni < 4; ++ni)
    boff[ni] = 32768 + ((lane >> 4) << 12) + (wn + ni * 16 + (lane & 15)) * 16;

  const int NT = K >> 6;

  // prologue: stage tile 0 into buf0 (8 loads); force Ak0,Bk0 (leave Ak1,Bk1 in flight)
  STG(gsrcA, 0, 0, 0);
  STG(gsrcB, 0, 0, 32768);
  STG(gsrcA, 0, 1, 16384);
  STG(gsrcB, 0, 1, 49152);
  WAITV4();
  BAR();

  bfrag_t af[8], bf[2];

  for (int t = 0; t + 1 < NT; ++t) {
    const int bc = (t & 1) << 16;
    const int bn = bc ^ 65536;
    const char* base = lds + bc;
    const int tn = t + 1;

    // phase 0
    LOAD_A(0);
    LOAD_B2(0, 1, 0);
    STG(gsrcA, tn, 0, bn);
    CLUSTER(0, 1);
    // phase 1
    LOAD_B2(2, 3, 0);
    STG(gsrcB, tn, 0, bn + 32768);
    WAITV4();
    CLUSTER(2, 3);
    // phase 2
    LOAD_A(16384);
    LOAD_B2(0, 1, 16384);
    STG(gsrcA, tn, 1, bn + 16384);
    CLUSTER(0, 1);
    // phase 3
    LOAD_B2(2, 3, 16384);
    STG(gsrcB, tn, 1, bn + 49152);
    WAITV4();
    CLUSTER(2, 3);
  }

  // peeled last tile: no staging; drain remaining (Ak1,Bk1 of this tile) at p1
  {
    const char* base = lds + (((NT - 1) & 1) << 16);
    LOAD_A(0);
    LOAD_B2(0, 1, 0);
    CLUSTER(0, 1);
    LOAD_B2(2, 3, 0);
    WAITV0();
    CLUSTER(2, 3);
    LOAD_A(16384);
    LOAD_B2(0, 1, 16384);
    CLUSTER(0, 1);
    LOAD_B2(2, 3, 16384);
    CLUSTER(2, 3);
  }

  BAR();  // all reads done before LDS reuse

  const int rq = lane >> 4, cs = lane & 15;
  if (MODE == 0) {
    // LDS-bounce epilogue: full 128B-line bf16 stores
    float bv[4];
#pragma unroll
    for (int ni = 0; ni < 4; ++ni) bv[ni] = bz[n0 + wn + ni * 16 + cs];
    unsigned short* wbase = (unsigned short*)(lds + wave * 2304);
#pragma unroll
    for (int mi = 0; mi < 8; ++mi) {
#pragma unroll
      for (int ni = 0; ni < 4; ++ni)
#pragma unroll
        for (int r = 0; r < 4; ++r) {
          float v = acc[mi][ni][r] + bv[ni];
          wbase[(rq * 4 + r) * 72 + ni * 16 + cs] = f2bf(gelu_tanh(v));
        }
      const int rrow = lane >> 3, uu = lane & 7;
      uint4 v0 = *(const uint4*)((const char*)wbase + rrow * 144 + uu * 16);
      uint4 v1 = *(const uint4*)((const char*)wbase + (rrow + 8) * 144 + uu * 16);
      unsigned short* orow0 =
          outB + ((size_t)zb * M + m0 + wm + mi * 16 + rrow) * N + n0 + wn + uu * 8;
      unsigned short* orow1 =
          outB + ((size_t)zb * M + m0 + wm + mi * 16 + rrow + 8) * N + n0 + wn + uu * 8;
      *(uint4*)orow0 = v0;
      *(uint4*)orow1 = v1;
    }
  } else {
#pragma unroll
    for (int ni = 0; ni < 4; ++ni) {
      const int n = n0 + wn + ni * 16 + cs;
      const float bv = bz[n];
#pragma unroll
      for (int mi = 0; mi < 8; ++mi)
#pragma unroll
        for (int r = 0; r < 4; ++r) {
          const int m = m0 + wm + mi * 16 + rq * 4 + r;
          outF[(size_t)m * N + n] = acc[mi][ni][r] + bv;
        }
    }
  }
}

// ---------------- 128x128 kernel for the expert-2 scatter GEMM ----------------
__global__ __launch_bounds__(256) void k_gemm_scatter(
    const unsigned short* __restrict__ A, const unsigned short* __restrict__ Bt,
    const float* __restrict__ bias, float* __restrict__ outF,
    const int* __restrict__ tok, const float* __restrict__ scale, int M, int N, int K) {
  const int zb = blockIdx.z;
  A += (size_t)zb * M * K;
  Bt += (size_t)zb * N * K;
  const float* bz = bias + (size_t)zb * N;

  const int m0 = blockIdx.x * 128, n0 = blockIdx.y * 128;
  const int tid = threadIdx.x, wave = tid >> 6, lane = tid & 63;
  const int wm = (wave >> 1) * 64, wn = (wave & 1) * 64;

  __shared__ unsigned short As[128 * 64];
  __shared__ unsigned short Bs[128 * 64];

  ffrag_t acc[4][4];
#pragma unroll
  for (int i = 0; i < 4; ++i)
#pragma unroll
    for (int j = 0; j < 4; ++j)
#pragma unroll
      for (int r = 0; r < 4; ++r) acc[i][j][r] = 0.f;

  int rr[4], gg[4], lb[4];
#pragma unroll
  for (int it = 0; it < 4; ++it) {
    int L = it * 256 + wave * 64 + lane;
    rr[it] = L >> 3;
    gg[it] = (L & 7) ^ (rr[it] & 7);
    lb[it] = (it * 256 + wave * 64) * 16;
  }

  for (int kt = 0; kt < K; kt += 64) {
#pragma unroll
    for (int it = 0; it < 4; ++it) {
      const unsigned short* sA = A + (size_t)(m0 + rr[it]) * K + kt + gg[it] * 8;
      const unsigned short* sB = Bt + (size_t)(n0 + rr[it]) * K + kt + gg[it] * 8;
      __builtin_amdgcn_global_load_lds((const __attribute__((address_space(1))) unsigned int*)sA,
                                       (__attribute__((address_space(3))) unsigned int*)((char*)As + lb[it]),
                                       16, 0, 0);
      __builtin_amdgcn_global_load_lds((const __attribute__((address_space(1))) unsigned int*)sB,
                                       (__attribute__((address_space(3))) unsigned int*)((char*)Bs + lb[it]),
                                       16, 0, 0);
    }
    __syncthreads();
#pragma unroll
    for (int kk = 0; kk < 2; ++kk) {
      bfrag_t af2[4], bf2[4];
      const int gl = kk * 4 + (lane >> 4);
#pragma unroll
      for (int mi = 0; mi < 4; ++mi) {
        int r = wm + mi * 16 + (lane & 15);
        af2[mi] = *(const bfrag_t*)&As[r * 64 + ((gl ^ (r & 7)) * 8)];
      }
#pragma unroll
      for (int ni = 0; ni < 4; ++ni) {
        int r = wn + ni * 16 + (lane & 15);
        bf2[ni] = *(const bfrag_t*)&Bs[r * 64 + ((gl ^ (r & 7)) * 8)];
      }
#pragma unroll
      for (int mi = 0; mi < 4; ++mi)
#pragma unroll
        for (int ni = 0; ni < 4; ++ni)
          acc[mi][ni] = __builtin_amdgcn_mfma_f32_16x16x32_bf16(af2[mi], bf2[ni], acc[mi][ni], 0, 0, 0);
    }
    __syncthreads();
  }

  const int rsub = (lane >> 4) * 4, csub = lane & 15;
#pragma unroll
  for (int ni = 0; ni < 4; ++ni) {
    const int n = n0 + wn + ni * 16 + csub;
    const float bv = bz[n];
#pragma unroll
    for (int mi = 0; mi < 4; ++mi) {
#pragma unroll
      for (int r = 0; r < 4; ++r) {
        const int m = m0 + wm + mi * 16 + rsub + r;
        float v = acc[mi][ni][r] + bv;
        const int t = tok[zb * M + m];
        const float s = scale[zb * M + m];
        atomicAdd(&outF[(size_t)t * N + n], v * s);
      }
    }
  }
}

extern "C" void kernel_launch(void* const* d_in, const int* in_sizes, int n_in,
                              void* d_out, int out_size, void* d_ws, size_t ws_size,
                              hipStream_t stream) {
  const float* x      = (const float*)d_in[0];
  const float* gate_w = (const float*)d_in[1];
  const float* gate_b = (const float*)d_in[2];
  const float* temp   = (const float*)d_in[3];
  const float* sw1    = (const float*)d_in[4];
  const float* sb1    = (const float*)d_in[5];
  const float* sw2    = (const float*)d_in[6];
  const float* sb2    = (const float*)d_in[7];
  const float* ew1    = (const float*)d_in[8];
  const float* eb1    = (const float*)d_in[9];
  const float* ew2    = (const float*)d_in[10];
  const float* eb2    = (const float*)d_in[11];
  float* out = (float*)d_out;

  char* ws = (char*)d_ws;
  size_t o = 0;
  auto take = [&](size_t bytes) { char* p = ws + o; o += (bytes + 255) & ~(size_t)255; return p; };
  unsigned short* x_bf = (unsigned short*)take((size_t)NTOK * DMODEL * 2);
  unsigned short* w1t  = (unsigned short*)take((size_t)DMODEL * DHID * 2);
  unsigned short* w2t  = (unsigned short*)take((size_t)DHID * DMODEL * 2);
  unsigned short* ew1t = (unsigned short*)take((size_t)NEXP * DMODEL * DHID * 2);
  unsigned short* ew2t = (unsigned short*)take((size_t)NEXP * DHID * DMODEL * 2);
  float* probs         = (float*)take((size_t)NEXP * NTOK * 4);
  int* tok             = (int*)take((size_t)NEXP * CAP * 4);
  float* scores        = (float*)take((size_t)NEXP * CAP * 4);
  int* eqbuf           = (int*)take((size_t)NEXP * NTOK * 4);
  unsigned short* atok = (unsigned short*)take((size_t)NEXP * CAP * DMODEL * 2);
  unsigned short* he   = (unsigned short*)take((size_t)NEXP * CAP * DHID * 2);
  unsigned short* hs   = (unsigned short*)take((size_t)NTOK * DHID * 2);

  // prep: bf16 conversions + weight transposes
  k_convert_bf16<<<4096, 256, 0, stream>>>(x, x_bf, NTOK * DMODEL / 4);
  k_trans_conv<<<dim3(DHID / 32, DMODEL / 32, 1), 256, 0, stream>>>(sw1, w1t, DMODEL, DHID);
  k_trans_conv<<<dim3(DMODEL / 32, DHID / 32, 1), 256, 0, stream>>>(sw2, w2t, DHID, DMODEL);
  k_trans_conv<<<dim3(DHID / 32, DMODEL / 32, NEXP), 256, 0, stream>>>(ew1, ew1t, DMODEL, DHID);
  k_trans_conv<<<dim3(DMODEL / 32, DHID / 32, NEXP), 256, 0, stream>>>(ew2, ew2t, DHID, DMODEL);

  // router + top-k + gather
  k_router<<<NTOK / 4, 256, 0, stream>>>(x, gate_w, gate_b, temp, probs);
  k_topk<<<NEXP, 256, 0, stream>>>(probs, tok, scores, eqbuf);
  k_gather<<<NEXP * CAP, 256, 0, stream>>>(x_bf, tok, atok);

  // shared FFN (256^2 4-phase pipelined kernel)
  k_gemm_big<0><<<dim3(NTOK / 256, DHID / 256, 1), 512, 0, stream>>>(
      x_bf, w1t, sb1, nullptr, hs, NTOK, DHID, DMODEL);
  k_gemm_big<1><<<dim3(NTOK / 256, DMODEL / 256, 1), 512, 0, stream>>>(
      hs, w2t, sb2, out, nullptr, NTOK, DMODEL, DHID);

  // routed experts: FFN-1 on the big kernel; FFN-2 scatter on 128^2 (256 blocks)
  k_gemm_big<0><<<dim3(CAP / 256, DHID / 256, NEXP), 512, 0, stream>>>(
      atok, ew1t, eb1, nullptr, he, CAP, DHID, DMODEL);
  k_gemm_scatter<<<dim3(CAP / 128, DMODEL / 128, NEXP), 256, 0, stream>>>(
      he, ew2t, eb2, out, tok, scores, CAP, DMODEL, DHID);
}

// Round 5
// 772.365 us; speedup vs baseline: 1.1817x; 1.1740x over previous
//
#include <hip/hip_runtime.h>

#define NTOK 16384
#define DMODEL 1024
#define DHID 4096
#define NEXP 8
#define CAP 512

typedef __attribute__((ext_vector_type(8))) short bfrag_t;
typedef __attribute__((ext_vector_type(4))) float ffrag_t;

__device__ __forceinline__ unsigned short f2bf(float f) {
  unsigned u = __float_as_uint(f);
  u += 0x7FFFu + ((u >> 16) & 1u);
  return (unsigned short)(u >> 16);
}

__device__ __forceinline__ float gelu_tanh(float x) {
  return 0.5f * x * (1.0f + tanhf(0.7978845608028654f * (x + 0.044715f * x * x * x)));
}

// ---------------- convert f32 -> bf16 flat ----------------
__global__ void k_convert_bf16(const float* __restrict__ in, unsigned short* __restrict__ out, int n4) {
  int i = blockIdx.x * blockDim.x + threadIdx.x;
  int stride = gridDim.x * blockDim.x;
  for (; i < n4; i += stride) {
    float4 v = ((const float4*)in)[i];
    ushort4 o;
    o.x = f2bf(v.x); o.y = f2bf(v.y); o.z = f2bf(v.z); o.w = f2bf(v.w);
    ((ushort4*)out)[i] = o;
  }
}

// ------------- transpose+convert: in [K,N] f32 -> out [N,K] bf16, batch z -------------
__global__ void k_trans_conv(const float* __restrict__ in, unsigned short* __restrict__ out, int K, int N) {
  const size_t zb = blockIdx.z;
  in  += zb * (size_t)K * N;
  out += zb * (size_t)N * K;
  __shared__ float tile[32][33];
  const int n0 = blockIdx.x * 32, k0 = blockIdx.y * 32;
  const int tx = threadIdx.x & 31, ty = threadIdx.x >> 5;
#pragma unroll
  for (int i = 0; i < 4; ++i) {
    int k = ty + i * 8;
    tile[k][tx] = in[(size_t)(k0 + k) * N + n0 + tx];
  }
  __syncthreads();
#pragma unroll
  for (int i = 0; i < 4; ++i) {
    int n = ty + i * 8;
    out[(size_t)(n0 + n) * K + k0 + tx] = f2bf(tile[tx][n]);
  }
}

// ---------------- router: probs[e][t] ----------------
__global__ __launch_bounds__(256) void k_router(const float* __restrict__ x, const float* __restrict__ gw,
                                                const float* __restrict__ gb, const float* __restrict__ temp,
                                                float* __restrict__ probs) {
  __shared__ float gws[DMODEL * NEXP];
  for (int i = threadIdx.x; i < DMODEL * NEXP; i += 256) gws[i] = gw[i];
  __syncthreads();
  const int wave = threadIdx.x >> 6, lane = threadIdx.x & 63;
  const int t = blockIdx.x * 4 + wave;
  const float* xr = x + (size_t)t * DMODEL;
  float acc[NEXP];
#pragma unroll
  for (int e = 0; e < NEXP; ++e) acc[e] = 0.f;
  for (int d = lane; d < DMODEL; d += 64) {
    float xv = xr[d];
#pragma unroll
    for (int e = 0; e < NEXP; ++e) acc[e] += xv * gws[d * NEXP + e];
  }
#pragma unroll
  for (int off = 32; off >= 1; off >>= 1) {
#pragma unroll
    for (int e = 0; e < NEXP; ++e) acc[e] += __shfl_xor(acc[e], off);
  }
  if (lane == 0) {
    float st = fmaxf(temp[0], 0.1f);
    float m = -1e30f;
#pragma unroll
    for (int e = 0; e < NEXP; ++e) { acc[e] = (acc[e] + gb[e]) / st; m = fmaxf(m, acc[e]); }
    float s = 0.f;
#pragma unroll
    for (int e = 0; e < NEXP; ++e) { acc[e] = expf(acc[e] - m); s += acc[e]; }
    float inv = 1.f / s;
#pragma unroll
    for (int e = 0; e < NEXP; ++e) probs[(size_t)e * NTOK + t] = acc[e] * inv;
  }
}

// ---------------- exact top-512 per expert (radix select, tie -> lowest index) ----------------
__global__ __launch_bounds__(256) void k_topk(const float* __restrict__ probs, int* __restrict__ tok,
                                              float* __restrict__ scores, int* __restrict__ eqbuf) {
  const int e = blockIdx.x;
  const float* p = probs + (size_t)e * NTOK;
  int* eq = eqbuf + (size_t)e * NTOK;
  __shared__ int hist[256];
  __shared__ unsigned sh_pref;
  __shared__ int sh_k, sh_gt, sh_eq, sh_cnt;
  const int tid = threadIdx.x;
  if (tid == 0) { sh_pref = 0u; sh_k = CAP; }
  __syncthreads();
  for (int pass = 3; pass >= 0; --pass) {
    hist[tid] = 0;
    __syncthreads();
    const unsigned pref = sh_pref;
    const int shift = pass * 8;
    for (int t = tid; t < NTOK; t += 256) {
      unsigned key = __float_as_uint(p[t]);
      bool cand = (pass == 3) || ((key >> (shift + 8)) == pref);
      if (cand) atomicAdd(&hist[(key >> shift) & 255], 1);
    }
    __syncthreads();
    if (tid == 0) {
      int k = sh_k;
      int d = 255;
      while (hist[d] < k) { k -= hist[d]; --d; }
      sh_k = k;
      sh_pref = (pref << 8) | (unsigned)d;
    }
    __syncthreads();
  }
  const unsigned Kstar = sh_pref;
  const int need_eq = sh_k;
  if (tid == 0) { sh_gt = 0; sh_eq = 0; }
  __syncthreads();
  for (int t = tid; t < NTOK; t += 256) {
    unsigned key = __float_as_uint(p[t]);
    if (key > Kstar) {
      int pos = atomicAdd(&sh_gt, 1);
      tok[e * CAP + pos] = t;
      scores[e * CAP + pos] = p[t];
    } else if (key == Kstar) {
      int q = atomicAdd(&sh_eq, 1);
      eq[q] = t;
    }
  }
  __syncthreads();
  const int cg = sh_gt, ce = sh_eq;
  if (ce <= need_eq) {
    for (int j = tid; j < ce; j += 256) {
      tok[e * CAP + cg + j] = eq[j];
      scores[e * CAP + cg + j] = p[eq[j]];
    }
  } else {
    int lo = 0, hi = NTOK - 1;
    while (lo < hi) {
      int mid = (lo + hi) >> 1;
      if (tid == 0) sh_cnt = 0;
      __syncthreads();
      for (int j = tid; j < ce; j += 256)
        if (eq[j] <= mid) atomicAdd(&sh_cnt, 1);
      __syncthreads();
      if (sh_cnt >= need_eq) hi = mid; else lo = mid + 1;
      __syncthreads();
    }
    if (tid == 0) sh_cnt = 0;
    __syncthreads();
    for (int j = tid; j < ce; j += 256) {
      if (eq[j] <= lo) {
        int pos = cg + atomicAdd(&sh_cnt, 1);
        tok[e * CAP + pos] = eq[j];
        scores[e * CAP + pos] = p[eq[j]];
      }
    }
  }
}

// ---------------- gather selected tokens (bf16 rows) ----------------
__global__ void k_gather(const unsigned short* __restrict__ xb, const int* __restrict__ tok,
                         unsigned short* __restrict__ atok) {
  const int row = blockIdx.x;
  const int t = tok[row];
  const uint2* src = (const uint2*)(xb + (size_t)t * DMODEL);
  uint2* dst = (uint2*)(atok + (size_t)row * DMODEL);
  dst[threadIdx.x] = src[threadIdx.x];
}

// =====================================================================================
// 256x256 tile, BK=32, 8 waves (2M x 4N), RING-4 LDS (4 x 32KB), one phase per K-step:
//   { STAGE(t+2) ; ds_reads(t) [pre-barrier, latency hidden] ; vmcnt(4) ; s_barrier ;
//     lgkm (compiler) ; setprio(1) ; 32 MFMA ; setprio(0) }
// COALESCED staging: thread L=j*512+tid -> row=L>>2, slot=L&3; 4 lanes = 64B contiguous
// row segment (source granule pre-permuted g = slot ^ (row&3)); LDS dest LINEAR (L*16).
// LDS layout per 32KB buf: A [256 rows][64B] @0, B @16384; read swizzle slot =
// (lane>>4)^(lane&3) (4-way residual conflict accepted).
// Landing proof (induction): wait at iter t has outstanding = {t+1 grp(4), t+2 grp(4)}
// -> vmcnt(4) forces t+1; barrier publishes to all waves; reads(t+1) issue only after
// that barrier. Write-race: STAGE(t+2) overwrites buf of t-2, whose reads completed
// before iter t-1's barrier. Tail: peel t=NT-2 (vmcnt(0)) and t=NT-1 (no wait).
// =====================================================================================

#define WAITV4() asm volatile("s_waitcnt vmcnt(4)" ::: "memory")
#define WAITV0() asm volatile("s_waitcnt vmcnt(0)" ::: "memory")
#define BAR()                                  \
  do {                                         \
    asm volatile("" ::: "memory");             \
    __builtin_amdgcn_s_barrier();              \
    asm volatile("" ::: "memory");             \
  } while (0)

#define GLDS(SRCP, DSTOFF)                                                                   \
  __builtin_amdgcn_global_load_lds(                                                         \
      (const __attribute__((address_space(1))) unsigned int*)(SRCP),                        \
      (__attribute__((address_space(3))) unsigned int*)(lds + (DSTOFF)), 16, 0, 0)

#define STAGE(TT)                                                                            \
  do {                                                                                       \
    const int _bb = ((TT) & 3) << 15;                                                        \
    _Pragma("unroll") for (int _j = 0; _j < 2; ++_j) {                                       \
      GLDS(gsrcA[_j] + (size_t)(TT) * 32, _bb + _j * 8192 + wave * 1024);                    \
      GLDS(gsrcB[_j] + (size_t)(TT) * 32, _bb + 16384 + _j * 8192 + wave * 1024);            \
    }                                                                                        \
  } while (0)

#define READS(T)                                                                             \
  const char* bb = lds + (((T) & 3) << 15);                                                  \
  bfrag_t af[8], bfr[4];                                                                     \
  _Pragma("unroll") for (int _mi = 0; _mi < 8; ++_mi)                                        \
      af[_mi] = *(const bfrag_t*)(bb + aoff[_mi]);                                           \
  _Pragma("unroll") for (int _ni = 0; _ni < 4; ++_ni)                                        \
      bfr[_ni] = *(const bfrag_t*)(bb + boff[_ni]);

#define MFMA32()                                                                             \
  __builtin_amdgcn_s_setprio(1);                                                             \
  _Pragma("unroll") for (int _m = 0; _m < 8; ++_m) {                                         \
    _Pragma("unroll") for (int _n = 0; _n < 4; ++_n)                                         \
        acc[_m][_n] =                                                                        \
            __builtin_amdgcn_mfma_f32_16x16x32_bf16(af[_m], bfr[_n], acc[_m][_n], 0, 0, 0);  \
  }                                                                                          \
  __builtin_amdgcn_s_setprio(0)

// MODE 0: outB[(zb*M+m)*N+n] = bf16(gelu(v))   MODE 1: outF[m*N+n] = v
template <int MODE>
__global__ __launch_bounds__(512, 2) void k_gemm_big(
    const unsigned short* __restrict__ A, const unsigned short* __restrict__ Bt,
    const float* __restrict__ bias, float* __restrict__ outF, unsigned short* __restrict__ outB,
    int M, int N, int K) {
  const int zb = blockIdx.z;
  A += (size_t)zb * M * K;
  Bt += (size_t)zb * N * K;
  const float* bz = bias + (size_t)zb * N;

  // T1: slab XCD swizzle (32 concurrent blocks/XCD share 8 A-panels + <=4 B-panels)
  const int gx = gridDim.x, gy = gridDim.y;
  const int nwg = gx * gy;
  const int id = blockIdx.x + blockIdx.y * gx;
  int bx, by;
  if ((gx & 7) == 0) {
    const int x = id & 7, c = id >> 3, H = gx >> 3;
    bx = x * H + (c % H);
    by = c / H;
  } else {
    const int q = nwg >> 3;
    const int sw = (id & 7) * q + (id >> 3);
    bx = sw % gx;
    by = sw / gx;
  }
  const int m0 = bx * 256, n0 = by * 256;

  const int tid = threadIdx.x, wave = tid >> 6, lane = tid & 63;
  const int wm = (wave >> 2) * 128;
  const int wn = (wave & 3) * 64;

  __shared__ alignas(16) char lds[131072];

  ffrag_t acc[8][4];
#pragma unroll
  for (int i = 0; i < 8; ++i)
#pragma unroll
    for (int j = 0; j < 4; ++j)
#pragma unroll
      for (int r = 0; r < 4; ++r) acc[i][j][r] = 0.f;

  // coalesced staging sources (granule pre-permuted by the read swizzle involution)
  const unsigned short* gsrcA[2];
  const unsigned short* gsrcB[2];
#pragma unroll
  for (int j = 0; j < 2; ++j) {
    const int L = j * 512 + tid;
    const int row = L >> 2;
    const int g = (L & 3) ^ (row & 3);
    gsrcA[j] = A + (size_t)(m0 + row) * K + g * 8;
    gsrcB[j] = Bt + (size_t)(n0 + row) * K + g * 8;
  }

  // read byte offsets: row*64 + ((lane>>4)^(row&3))*16 ; note row&3 == lane&3
  const int sw16 = (((lane >> 4) ^ (lane & 3)) << 4);
  int aoff[8], boff[4];
#pragma unroll
  for (int mi = 0; mi < 8; ++mi)
    aoff[mi] = (wm + mi * 16 + (lane & 15)) * 64 + sw16;
#pragma unroll
  for (int ni = 0; ni < 4; ++ni)
    boff[ni] = 16384 + (wn + ni * 16 + (lane & 15)) * 64 + sw16;

  const int NT = K >> 5;

  // prologue: 2 K-steps in flight; force K-step 0 (vmcnt(4) keeps K-step 1 flying)
  STAGE(0);
  STAGE(1);
  WAITV4();
  BAR();

  for (int t = 0; t < NT - 2; ++t) {
    STAGE(t + 2);
    READS(t);
    WAITV4();  // forces K-step t+1 (outstanding: t+1 grp + t+2 grp)
    BAR();
    MFMA32();
  }
  {  // t = NT-2: no stage; drain K-step NT-1
    READS(NT - 2);
    WAITV0();
    BAR();
    MFMA32();
  }
  {  // t = NT-1: everything landed and published
    READS(NT - 1);
    MFMA32();
  }

  BAR();  // all LDS reads consumed before epilogue scratch reuse

  const int rq = lane >> 4, cs = lane & 15;
  if (MODE == 0) {
    // LDS-bounce epilogue: full 128B-line bf16 stores
    float bv[4];
#pragma unroll
    for (int ni = 0; ni < 4; ++ni) bv[ni] = bz[n0 + wn + ni * 16 + cs];
    unsigned short* wbase = (unsigned short*)(lds + wave * 2304);
#pragma unroll
    for (int mi = 0; mi < 8; ++mi) {
#pragma unroll
      for (int ni = 0; ni < 4; ++ni)
#pragma unroll
        for (int r = 0; r < 4; ++r) {
          float v = acc[mi][ni][r] + bv[ni];
          wbase[(rq * 4 + r) * 72 + ni * 16 + cs] = f2bf(gelu_tanh(v));
        }
      const int rrow = lane >> 3, uu = lane & 7;
      uint4 v0 = *(const uint4*)((const char*)wbase + rrow * 144 + uu * 16);
      uint4 v1 = *(const uint4*)((const char*)wbase + (rrow + 8) * 144 + uu * 16);
      unsigned short* orow0 =
          outB + ((size_t)zb * M + m0 + wm + mi * 16 + rrow) * N + n0 + wn + uu * 8;
      unsigned short* orow1 =
          outB + ((size_t)zb * M + m0 + wm + mi * 16 + rrow + 8) * N + n0 + wn + uu * 8;
      *(uint4*)orow0 = v0;
      *(uint4*)orow1 = v1;
    }
  } else {
#pragma unroll
    for (int ni = 0; ni < 4; ++ni) {
      const int n = n0 + wn + ni * 16 + cs;
      const float bv = bz[n];
#pragma unroll
      for (int mi = 0; mi < 8; ++mi)
#pragma unroll
        for (int r = 0; r < 4; ++r) {
          const int m = m0 + wm + mi * 16 + rq * 4 + r;
          outF[(size_t)m * N + n] = acc[mi][ni][r] + bv;
        }
    }
  }
}

// ---------------- 128x128 kernel for the expert-2 scatter GEMM ----------------
__global__ __launch_bounds__(256) void k_gemm_scatter(
    const unsigned short* __restrict__ A, const unsigned short* __restrict__ Bt,
    const float* __restrict__ bias, float* __restrict__ outF,
    const int* __restrict__ tok, const float* __restrict__ scale, int M, int N, int K) {
  const int zb = blockIdx.z;
  A += (size_t)zb * M * K;
  Bt += (size_t)zb * N * K;
  const float* bz = bias + (size_t)zb * N;

  const int m0 = blockIdx.x * 128, n0 = blockIdx.y * 128;
  const int tid = threadIdx.x, wave = tid >> 6, lane = tid & 63;
  const int wm = (wave >> 1) * 64, wn = (wave & 1) * 64;

  __shared__ unsigned short As[128 * 64];
  __shared__ unsigned short Bs[128 * 64];

  ffrag_t acc[4][4];
#pragma unroll
  for (int i = 0; i < 4; ++i)
#pragma unroll
    for (int j = 0; j < 4; ++j)
#pragma unroll
      for (int r = 0; r < 4; ++r) acc[i][j][r] = 0.f;

  int rr[4], gg[4], lb[4];
#pragma unroll
  for (int it = 0; it < 4; ++it) {
    int L = it * 256 + wave * 64 + lane;
    rr[it] = L >> 3;
    gg[it] = (L & 7) ^ (rr[it] & 7);
    lb[it] = (it * 256 + wave * 64) * 16;
  }

  for (int kt = 0; kt < K; kt += 64) {
#pragma unroll
    for (int it = 0; it < 4; ++it) {
      const unsigned short* sA = A + (size_t)(m0 + rr[it]) * K + kt + gg[it] * 8;
      const unsigned short* sB = Bt + (size_t)(n0 + rr[it]) * K + kt + gg[it] * 8;
      __builtin_amdgcn_global_load_lds((const __attribute__((address_space(1))) unsigned int*)sA,
                                       (__attribute__((address_space(3))) unsigned int*)((char*)As + lb[it]),
                                       16, 0, 0);
      __builtin_amdgcn_global_load_lds((const __attribute__((address_space(1))) unsigned int*)sB,
                                       (__attribute__((address_space(3))) unsigned int*)((char*)Bs + lb[it]),
                                       16, 0, 0);
    }
    __syncthreads();
#pragma unroll
    for (int kk = 0; kk < 2; ++kk) {
      bfrag_t af2[4], bf2[4];
      const int gl = kk * 4 + (lane >> 4);
#pragma unroll
      for (int mi = 0; mi < 4; ++mi) {
        int r = wm + mi * 16 + (lane & 15);
        af2[mi] = *(const bfrag_t*)&As[r * 64 + ((gl ^ (r & 7)) * 8)];
      }
#pragma unroll
      for (int ni = 0; ni < 4; ++ni) {
        int r = wn + ni * 16 + (lane & 15);
        bf2[ni] = *(const bfrag_t*)&Bs[r * 64 + ((gl ^ (r & 7)) * 8)];
      }
#pragma unroll
      for (int mi = 0; mi < 4; ++mi)
#pragma unroll
        for (int ni = 0; ni < 4; ++ni)
          acc[mi][ni] = __builtin_amdgcn_mfma_f32_16x16x32_bf16(af2[mi], bf2[ni], acc[mi][ni], 0, 0, 0);
    }
    __syncthreads();
  }

  const int rsub = (lane >> 4) * 4, csub = lane & 15;
#pragma unroll
  for (int ni = 0; ni < 4; ++ni) {
    const int n = n0 + wn + ni * 16 + csub;
    const float bv = bz[n];
#pragma unroll
    for (int mi = 0; mi < 4; ++mi) {
#pragma unroll
      for (int r = 0; r < 4; ++r) {
        const int m = m0 + wm + mi * 16 + rsub + r;
        float v = acc[mi][ni][r] + bv;
        const int t = tok[zb * M + m];
        const float s = scale[zb * M + m];
        atomicAdd(&outF[(size_t)t * N + n], v * s);
      }
    }
  }
}

extern "C" void kernel_launch(void* const* d_in, const int* in_sizes, int n_in,
                              void* d_out, int out_size, void* d_ws, size_t ws_size,
                              hipStream_t stream) {
  const float* x      = (const float*)d_in[0];
  const float* gate_w = (const float*)d_in[1];
  const float* gate_b = (const float*)d_in[2];
  const float* temp   = (const float*)d_in[3];
  const float* sw1    = (const float*)d_in[4];
  const float* sb1    = (const float*)d_in[5];
  const float* sw2    = (const float*)d_in[6];
  const float* sb2    = (const float*)d_in[7];
  const float* ew1    = (const float*)d_in[8];
  const float* eb1    = (const float*)d_in[9];
  const float* ew2    = (const float*)d_in[10];
  const float* eb2    = (const float*)d_in[11];
  float* out = (float*)d_out;

  char* ws = (char*)d_ws;
  size_t o = 0;
  auto take = [&](size_t bytes) { char* p = ws + o; o += (bytes + 255) & ~(size_t)255; return p; };
  unsigned short* x_bf = (unsigned short*)take((size_t)NTOK * DMODEL * 2);
  unsigned short* w1t  = (unsigned short*)take((size_t)DMODEL * DHID * 2);
  unsigned short* w2t  = (unsigned short*)take((size_t)DHID * DMODEL * 2);
  unsigned short* ew1t = (unsigned short*)take((size_t)NEXP * DMODEL * DHID * 2);
  unsigned short* ew2t = (unsigned short*)take((size_t)NEXP * DHID * DMODEL * 2);
  float* probs         = (float*)take((size_t)NEXP * NTOK * 4);
  int* tok             = (int*)take((size_t)NEXP * CAP * 4);
  float* scores        = (float*)take((size_t)NEXP * CAP * 4);
  int* eqbuf           = (int*)take((size_t)NEXP * NTOK * 4);
  unsigned short* atok = (unsigned short*)take((size_t)NEXP * CAP * DMODEL * 2);
  unsigned short* he   = (unsigned short*)take((size_t)NEXP * CAP * DHID * 2);
  unsigned short* hs   = (unsigned short*)take((size_t)NTOK * DHID * 2);

  // prep: bf16 conversions + weight transposes
  k_convert_bf16<<<4096, 256, 0, stream>>>(x, x_bf, NTOK * DMODEL / 4);
  k_trans_conv<<<dim3(DHID / 32, DMODEL / 32, 1), 256, 0, stream>>>(sw1, w1t, DMODEL, DHID);
  k_trans_conv<<<dim3(DMODEL / 32, DHID / 32, 1), 256, 0, stream>>>(sw2, w2t, DHID, DMODEL);
  k_trans_conv<<<dim3(DHID / 32, DMODEL / 32, NEXP), 256, 0, stream>>>(ew1, ew1t, DMODEL, DHID);
  k_trans_conv<<<dim3(DMODEL / 32, DHID / 32, NEXP), 256, 0, stream>>>(ew2, ew2t, DHID, DMODEL);

  // router + top-k + gather
  k_router<<<NTOK / 4, 256, 0, stream>>>(x, gate_w, gate_b, temp, probs);
  k_topk<<<NEXP, 256, 0, stream>>>(probs, tok, scores, eqbuf);
  k_gather<<<NEXP * CAP, 256, 0, stream>>>(x_bf, tok, atok);

  // shared FFN (256^2 ring-4 pipelined kernel)
  k_gemm_big<0><<<dim3(NTOK / 256, DHID / 256, 1), 512, 0, stream>>>(
      x_bf, w1t, sb1, nullptr, hs, NTOK, DHID, DMODEL);
  k_gemm_big<1><<<dim3(NTOK / 256, DMODEL / 256, 1), 512, 0, stream>>>(
      hs, w2t, sb2, out, nullptr, NTOK, DMODEL, DHID);

  // routed experts: FFN-1 on the big kernel; FFN-2 scatter on 128^2 (256 blocks)
  k_gemm_big<0><<<dim3(CAP / 256, DHID / 256, NEXP), 512, 0, stream>>>(
      atok, ew1t, eb1, nullptr, he, CAP, DHID, DMODEL);
  k_gemm_scatter<<<dim3(CAP / 128, DMODEL / 128, NEXP), 256, 0, stream>>>(
      he, ew2t, eb2, out, tok, scores, CAP, DMODEL, DHID);
}

// Round 6
// 765.347 us; speedup vs baseline: 1.1925x; 1.0092x over previous
//
#include <hip/hip_runtime.h>

#define NTOK 16384
#define DMODEL 1024
#define DHID 4096
#define NEXP 8
#define CAP 512

typedef __attribute__((ext_vector_type(8))) short bfrag_t;
typedef __attribute__((ext_vector_type(4))) float ffrag_t;

__device__ __forceinline__ unsigned short f2bf(float f) {
  unsigned u = __float_as_uint(f);
  u += 0x7FFFu + ((u >> 16) & 1u);
  return (unsigned short)(u >> 16);
}

__device__ __forceinline__ float gelu_tanh(float x) {
  return 0.5f * x * (1.0f + tanhf(0.7978845608028654f * (x + 0.044715f * x * x * x)));
}

// ---------------- convert f32 -> bf16 flat ----------------
__global__ void k_convert_bf16(const float* __restrict__ in, unsigned short* __restrict__ out, int n4) {
  int i = blockIdx.x * blockDim.x + threadIdx.x;
  int stride = gridDim.x * blockDim.x;
  for (; i < n4; i += stride) {
    float4 v = ((const float4*)in)[i];
    ushort4 o;
    o.x = f2bf(v.x); o.y = f2bf(v.y); o.z = f2bf(v.z); o.w = f2bf(v.w);
    ((ushort4*)out)[i] = o;
  }
}

// ------------- transpose+convert: in [K,N] f32 -> out [N,K] bf16, batch z -------------
__global__ void k_trans_conv(const float* __restrict__ in, unsigned short* __restrict__ out, int K, int N) {
  const size_t zb = blockIdx.z;
  in  += zb * (size_t)K * N;
  out += zb * (size_t)N * K;
  __shared__ float tile[32][33];
  const int n0 = blockIdx.x * 32, k0 = blockIdx.y * 32;
  const int tx = threadIdx.x & 31, ty = threadIdx.x >> 5;
#pragma unroll
  for (int i = 0; i < 4; ++i) {
    int k = ty + i * 8;
    tile[k][tx] = in[(size_t)(k0 + k) * N + n0 + tx];
  }
  __syncthreads();
#pragma unroll
  for (int i = 0; i < 4; ++i) {
    int n = ty + i * 8;
    out[(size_t)(n0 + n) * K + k0 + tx] = f2bf(tile[tx][n]);
  }
}

// ---------------- router: probs[e][t] ----------------
__global__ __launch_bounds__(256) void k_router(const float* __restrict__ x, const float* __restrict__ gw,
                                                const float* __restrict__ gb, const float* __restrict__ temp,
                                                float* __restrict__ probs) {
  __shared__ float gws[DMODEL * NEXP];
  for (int i = threadIdx.x; i < DMODEL * NEXP; i += 256) gws[i] = gw[i];
  __syncthreads();
  const int wave = threadIdx.x >> 6, lane = threadIdx.x & 63;
  const int t = blockIdx.x * 4 + wave;
  const float* xr = x + (size_t)t * DMODEL;
  float acc[NEXP];
#pragma unroll
  for (int e = 0; e < NEXP; ++e) acc[e] = 0.f;
  for (int d = lane; d < DMODEL; d += 64) {
    float xv = xr[d];
#pragma unroll
    for (int e = 0; e < NEXP; ++e) acc[e] += xv * gws[d * NEXP + e];
  }
#pragma unroll
  for (int off = 32; off >= 1; off >>= 1) {
#pragma unroll
    for (int e = 0; e < NEXP; ++e) acc[e] += __shfl_xor(acc[e], off);
  }
  if (lane == 0) {
    float st = fmaxf(temp[0], 0.1f);
    float m = -1e30f;
#pragma unroll
    for (int e = 0; e < NEXP; ++e) { acc[e] = (acc[e] + gb[e]) / st; m = fmaxf(m, acc[e]); }
    float s = 0.f;
#pragma unroll
    for (int e = 0; e < NEXP; ++e) { acc[e] = expf(acc[e] - m); s += acc[e]; }
    float inv = 1.f / s;
#pragma unroll
    for (int e = 0; e < NEXP; ++e) probs[(size_t)e * NTOK + t] = acc[e] * inv;
  }
}

// ---------------- exact top-512 per expert (radix select, tie -> lowest index) ----------------
__global__ __launch_bounds__(256) void k_topk(const float* __restrict__ probs, int* __restrict__ tok,
                                              float* __restrict__ scores, int* __restrict__ eqbuf) {
  const int e = blockIdx.x;
  const float* p = probs + (size_t)e * NTOK;
  int* eq = eqbuf + (size_t)e * NTOK;
  __shared__ int hist[256];
  __shared__ unsigned sh_pref;
  __shared__ int sh_k, sh_gt, sh_eq, sh_cnt;
  const int tid = threadIdx.x;
  if (tid == 0) { sh_pref = 0u; sh_k = CAP; }
  __syncthreads();
  for (int pass = 3; pass >= 0; --pass) {
    hist[tid] = 0;
    __syncthreads();
    const unsigned pref = sh_pref;
    const int shift = pass * 8;
    for (int t = tid; t < NTOK; t += 256) {
      unsigned key = __float_as_uint(p[t]);
      bool cand = (pass == 3) || ((key >> (shift + 8)) == pref);
      if (cand) atomicAdd(&hist[(key >> shift) & 255], 1);
    }
    __syncthreads();
    if (tid == 0) {
      int k = sh_k;
      int d = 255;
      while (hist[d] < k) { k -= hist[d]; --d; }
      sh_k = k;
      sh_pref = (pref << 8) | (unsigned)d;
    }
    __syncthreads();
  }
  const unsigned Kstar = sh_pref;
  const int need_eq = sh_k;
  if (tid == 0) { sh_gt = 0; sh_eq = 0; }
  __syncthreads();
  for (int t = tid; t < NTOK; t += 256) {
    unsigned key = __float_as_uint(p[t]);
    if (key > Kstar) {
      int pos = atomicAdd(&sh_gt, 1);
      tok[e * CAP + pos] = t;
      scores[e * CAP + pos] = p[t];
    } else if (key == Kstar) {
      int q = atomicAdd(&sh_eq, 1);
      eq[q] = t;
    }
  }
  __syncthreads();
  const int cg = sh_gt, ce = sh_eq;
  if (ce <= need_eq) {
    for (int j = tid; j < ce; j += 256) {
      tok[e * CAP + cg + j] = eq[j];
      scores[e * CAP + cg + j] = p[eq[j]];
    }
  } else {
    int lo = 0, hi = NTOK - 1;
    while (lo < hi) {
      int mid = (lo + hi) >> 1;
      if (tid == 0) sh_cnt = 0;
      __syncthreads();
      for (int j = tid; j < ce; j += 256)
        if (eq[j] <= mid) atomicAdd(&sh_cnt, 1);
      __syncthreads();
      if (sh_cnt >= need_eq) hi = mid; else lo = mid + 1;
      __syncthreads();
    }
    if (tid == 0) sh_cnt = 0;
    __syncthreads();
    for (int j = tid; j < ce; j += 256) {
      if (eq[j] <= lo) {
        int pos = cg + atomicAdd(&sh_cnt, 1);
        tok[e * CAP + pos] = eq[j];
        scores[e * CAP + pos] = p[eq[j]];
      }
    }
  }
}

// ---------------- gather selected tokens (bf16 rows) ----------------
__global__ void k_gather(const unsigned short* __restrict__ xb, const int* __restrict__ tok,
                         unsigned short* __restrict__ atok) {
  const int row = blockIdx.x;
  const int t = tok[row];
  const uint2* src = (const uint2*)(xb + (size_t)t * DMODEL);
  uint2* dst = (uint2*)(atok + (size_t)row * DMODEL);
  dst[threadIdx.x] = src[threadIdx.x];
}

// =====================================================================================
// 256x256 tile, BK=32, 8 waves (2M x 4N), RING-4 LDS (4 x 32KB), TWO PHASES per K-step.
// LDS buffer layout (32KB): 256 rows x 128B. Row r = { A-row-r 64B | B-row-r 64B },
// slot-swizzled: byte slot sc (0..7, 16B each) at row r holds content c = sc ^ (r&7);
// c in 0..3 -> A[r][k16=c], c in 4..7 -> B[r][k16=c-4].
//   * reads: lane l wants A[row][k16=l>>4] -> addr = row*128 + ((l>>4)^(l&7))*16;
//     B: addr = row*128 + (((l>>4)+4)^(l&7))*16. Bank-group = slot index: each of the
//     8 groups gets exactly 8 lanes -> conflict-free (1KB/128B floor).
//   * staging: slot s = j*512+tid (j=0..3) -> LDS byte s*16 (LINEAR dest, wave-uniform
//     base + lane*16); global source per-lane pre-permuted (mixes A/B pointers; 8
//     consecutive lanes cover A-row 64B + B-row 64B segments -> coalesced).
// Schedule per K-step t (ring-4: stage t+2, depth 2):
//   PA: read A(mi0-3)+B(all) [8 ds_read] ; stage j01(t+2) ; BAR ; MFMA mi0-3 (16) ; BAR
//   PB: read A(mi4-7)        [4 ds_read] ; stage j23(t+2) ; vmcnt(4) ; BAR ;
//       MFMA mi4-7 (16) ; BAR
// vmcnt(4) at t.PB: outstanding = stage(t+1)[4] + stage(t+2)[4] -> forces t+1 exactly;
// never 0 mid-loop. B-frags persist in regs across PA/PB. Tail: t=NT-2 waits 0, t=NT-1
// runs dry. Write-race: stage(t+2) overwrites buf(t-2), fully consumed before t-1's
// end barrier.
// =====================================================================================

#define WAITV4() asm volatile("s_waitcnt vmcnt(4)" ::: "memory")
#define WAITV0() asm volatile("s_waitcnt vmcnt(0)" ::: "memory")
#define BAR()                                  \
  do {                                         \
    asm volatile("" ::: "memory");             \
    __builtin_amdgcn_s_barrier();              \
    asm volatile("" ::: "memory");             \
  } while (0)

#define GLDS(SRCP, DSTOFF)                                                                   \
  __builtin_amdgcn_global_load_lds(                                                         \
      (const __attribute__((address_space(1))) unsigned int*)(SRCP),                        \
      (__attribute__((address_space(3))) unsigned int*)(lds + (DSTOFF)), 16, 0, 0)

// stage j-pair {J0, J0+1} of K-step TT into ring buffer (TT&3)
#define STAGE2(TT, J0)                                                                       \
  do {                                                                                       \
    const int _bb = ((TT) & 3) << 15;                                                        \
    GLDS(gsrc[J0] + (size_t)(TT) * 32, _bb + (((J0) * 512 + wave * 64) * 16));               \
    GLDS(gsrc[(J0) + 1] + (size_t)(TT) * 32, _bb + ((((J0) + 1) * 512 + wave * 64) * 16));   \
  } while (0)

#define MFMA16(AF, MBASE)                                                                     \
  __builtin_amdgcn_s_setprio(1);                                                             \
  _Pragma("unroll") for (int _m = 0; _m < 4; ++_m) {                                         \
    _Pragma("unroll") for (int _n = 0; _n < 4; ++_n)                                         \
        acc[(MBASE) + _m][_n] = __builtin_amdgcn_mfma_f32_16x16x32_bf16(                      \
            AF[_m], bfr[_n], acc[(MBASE) + _m][_n], 0, 0, 0);                                 \
  }                                                                                          \
  __builtin_amdgcn_s_setprio(0)

// MODE 0: outB[(zb*M+m)*N+n] = bf16(gelu(v))   MODE 1: outF[m*N+n] = v
template <int MODE>
__global__ __launch_bounds__(512, 2) void k_gemm_big(
    const unsigned short* __restrict__ A, const unsigned short* __restrict__ Bt,
    const float* __restrict__ bias, float* __restrict__ outF, unsigned short* __restrict__ outB,
    int M, int N, int K) {
  const int zb = blockIdx.z;
  A += (size_t)zb * M * K;
  Bt += (size_t)zb * N * K;
  const float* bz = bias + (size_t)zb * N;

  // T1: slab XCD swizzle (32 concurrent blocks/XCD share 8 A-panels + <=4 B-panels)
  const int gx = gridDim.x, gy = gridDim.y;
  const int nwg = gx * gy;
  const int id = blockIdx.x + blockIdx.y * gx;
  int bx, by;
  if ((gx & 7) == 0) {
    const int x = id & 7, c = id >> 3, H = gx >> 3;
    bx = x * H + (c % H);
    by = c / H;
  } else {
    const int q = nwg >> 3;
    const int sw = (id & 7) * q + (id >> 3);
    bx = sw % gx;
    by = sw / gx;
  }
  const int m0 = bx * 256, n0 = by * 256;

  const int tid = threadIdx.x, wave = tid >> 6, lane = tid & 63;
  const int wm = (wave >> 2) * 128;
  const int wn = (wave & 3) * 64;

  __shared__ alignas(16) char lds[131072];

  ffrag_t acc[8][4];
#pragma unroll
  for (int i = 0; i < 8; ++i)
#pragma unroll
    for (int j = 0; j < 4; ++j)
#pragma unroll
      for (int r = 0; r < 4; ++r) acc[i][j][r] = 0.f;

  // staging sources: slot s = j*512+tid -> row = s>>3, sc = s&7, content c = sc^(row&7)
  const unsigned short* gsrc[4];
#pragma unroll
  for (int j = 0; j < 4; ++j) {
    const int s = j * 512 + tid;
    const int row = s >> 3;
    const int c = (s & 7) ^ (row & 7);
    if (c < 4)
      gsrc[j] = A + (size_t)(m0 + row) * K + c * 8;
    else
      gsrc[j] = Bt + (size_t)(n0 + row) * K + (c - 4) * 8;
  }

  // read byte offsets within a ring buffer
  int aoff[8], boff[4];
#pragma unroll
  for (int mi = 0; mi < 8; ++mi) {
    const int row = wm + mi * 16 + (lane & 15);
    aoff[mi] = row * 128 + (((lane >> 4) ^ (lane & 7)) << 4);
  }
#pragma unroll
  for (int ni = 0; ni < 4; ++ni) {
    const int row = wn + ni * 16 + (lane & 15);
    boff[ni] = row * 128 + ((((lane >> 4) + 4) ^ (lane & 7)) << 4);
  }

  const int NT = K >> 5;

  // prologue: 2 K-steps in flight; force K-step 0 (leave K-step 1 flying)
  STAGE2(0, 0);
  STAGE2(0, 2);
  STAGE2(1, 0);
  STAGE2(1, 2);
  WAITV4();
  BAR();

  bfrag_t af[4], bfr[4];

  for (int t = 0; t < NT - 2; ++t) {
    const char* base = lds + ((t & 3) << 15);
    // ---- phase A: A-lo + B reads, stage j01(t+2), MFMA mi0-3 ----
#pragma unroll
    for (int i = 0; i < 4; ++i) af[i] = *(const bfrag_t*)(base + aoff[i]);
#pragma unroll
    for (int n = 0; n < 4; ++n) bfr[n] = *(const bfrag_t*)(base + boff[n]);
    STAGE2(t + 2, 0);
    BAR();
    MFMA16(af, 0);
    BAR();
    // ---- phase B: A-hi reads, stage j23(t+2), counted wait, MFMA mi4-7 ----
#pragma unroll
    for (int i = 0; i < 4; ++i) af[i] = *(const bfrag_t*)(base + aoff[4 + i]);
    STAGE2(t + 2, 2);
    WAITV4();
    BAR();
    MFMA16(af, 4);
    BAR();
  }
  {  // t = NT-2: no stage; drain K-step NT-1
    const char* base = lds + (((NT - 2) & 3) << 15);
#pragma unroll
    for (int i = 0; i < 4; ++i) af[i] = *(const bfrag_t*)(base + aoff[i]);
#pragma unroll
    for (int n = 0; n < 4; ++n) bfr[n] = *(const bfrag_t*)(base + boff[n]);
    BAR();
    MFMA16(af, 0);
    BAR();
#pragma unroll
    for (int i = 0; i < 4; ++i) af[i] = *(const bfrag_t*)(base + aoff[4 + i]);
    WAITV0();
    BAR();
    MFMA16(af, 4);
    BAR();
  }
  {  // t = NT-1: everything landed and published
    const char* base = lds + (((NT - 1) & 3) << 15);
#pragma unroll
    for (int i = 0; i < 4; ++i) af[i] = *(const bfrag_t*)(base + aoff[i]);
#pragma unroll
    for (int n = 0; n < 4; ++n) bfr[n] = *(const bfrag_t*)(base + boff[n]);
    MFMA16(af, 0);
#pragma unroll
    for (int i = 0; i < 4; ++i) af[i] = *(const bfrag_t*)(base + aoff[4 + i]);
    MFMA16(af, 4);
  }

  BAR();  // all LDS reads consumed before epilogue scratch reuse

  const int rq = lane >> 4, cs = lane & 15;
  if (MODE == 0) {
    // LDS-bounce epilogue: full 128B-line bf16 stores
    float bv[4];
#pragma unroll
    for (int ni = 0; ni < 4; ++ni) bv[ni] = bz[n0 + wn + ni * 16 + cs];
    unsigned short* wbase = (unsigned short*)(lds + wave * 2304);
#pragma unroll
    for (int mi = 0; mi < 8; ++mi) {
#pragma unroll
      for (int ni = 0; ni < 4; ++ni)
#pragma unroll
        for (int r = 0; r < 4; ++r) {
          float v = acc[mi][ni][r] + bv[ni];
          wbase[(rq * 4 + r) * 72 + ni * 16 + cs] = f2bf(gelu_tanh(v));
        }
      const int rrow = lane >> 3, uu = lane & 7;
      uint4 v0 = *(const uint4*)((const char*)wbase + rrow * 144 + uu * 16);
      uint4 v1 = *(const uint4*)((const char*)wbase + (rrow + 8) * 144 + uu * 16);
      unsigned short* orow0 =
          outB + ((size_t)zb * M + m0 + wm + mi * 16 + rrow) * N + n0 + wn + uu * 8;
      unsigned short* orow1 =
          outB + ((size_t)zb * M + m0 + wm + mi * 16 + rrow + 8) * N + n0 + wn + uu * 8;
      *(uint4*)orow0 = v0;
      *(uint4*)orow1 = v1;
    }
  } else {
#pragma unroll
    for (int ni = 0; ni < 4; ++ni) {
      const int n = n0 + wn + ni * 16 + cs;
      const float bv = bz[n];
#pragma unroll
      for (int mi = 0; mi < 8; ++mi)
#pragma unroll
        for (int r = 0; r < 4; ++r) {
          const int m = m0 + wm + mi * 16 + rq * 4 + r;
          outF[(size_t)m * N + n] = acc[mi][ni][r] + bv;
        }
    }
  }
}

// ---------------- 128x128 kernel for the expert-2 scatter GEMM ----------------
__global__ __launch_bounds__(256) void k_gemm_scatter(
    const unsigned short* __restrict__ A, const unsigned short* __restrict__ Bt,
    const float* __restrict__ bias, float* __restrict__ outF,
    const int* __restrict__ tok, const float* __restrict__ scale, int M, int N, int K) {
  const int zb = blockIdx.z;
  A += (size_t)zb * M * K;
  Bt += (size_t)zb * N * K;
  const float* bz = bias + (size_t)zb * N;

  const int m0 = blockIdx.x * 128, n0 = blockIdx.y * 128;
  const int tid = threadIdx.x, wave = tid >> 6, lane = tid & 63;
  const int wm = (wave >> 1) * 64, wn = (wave & 1) * 64;

  __shared__ unsigned short As[128 * 64];
  __shared__ unsigned short Bs[128 * 64];

  ffrag_t acc[4][4];
#pragma unroll
  for (int i = 0; i < 4; ++i)
#pragma unroll
    for (int j = 0; j < 4; ++j)
#pragma unroll
      for (int r = 0; r < 4; ++r) acc[i][j][r] = 0.f;

  int rr[4], gg[4], lb[4];
#pragma unroll
  for (int it = 0; it < 4; ++it) {
    int L = it * 256 + wave * 64 + lane;
    rr[it] = L >> 3;
    gg[it] = (L & 7) ^ (rr[it] & 7);
    lb[it] = (it * 256 + wave * 64) * 16;
  }

  for (int kt = 0; kt < K; kt += 64) {
#pragma unroll
    for (int it = 0; it < 4; ++it) {
      const unsigned short* sA = A + (size_t)(m0 + rr[it]) * K + kt + gg[it] * 8;
      const unsigned short* sB = Bt + (size_t)(n0 + rr[it]) * K + kt + gg[it] * 8;
      __builtin_amdgcn_global_load_lds((const __attribute__((address_space(1))) unsigned int*)sA,
                                       (__attribute__((address_space(3))) unsigned int*)((char*)As + lb[it]),
                                       16, 0, 0);
      __builtin_amdgcn_global_load_lds((const __attribute__((address_space(1))) unsigned int*)sB,
                                       (__attribute__((address_space(3))) unsigned int*)((char*)Bs + lb[it]),
                                       16, 0, 0);
    }
    __syncthreads();
#pragma unroll
    for (int kk = 0; kk < 2; ++kk) {
      bfrag_t af2[4], bf2[4];
      const int gl = kk * 4 + (lane >> 4);
#pragma unroll
      for (int mi = 0; mi < 4; ++mi) {
        int r = wm + mi * 16 + (lane & 15);
        af2[mi] = *(const bfrag_t*)&As[r * 64 + ((gl ^ (r & 7)) * 8)];
      }
#pragma unroll
      for (int ni = 0; ni < 4; ++ni) {
        int r = wn + ni * 16 + (lane & 15);
        bf2[ni] = *(const bfrag_t*)&Bs[r * 64 + ((gl ^ (r & 7)) * 8)];
      }
#pragma unroll
      for (int mi = 0; mi < 4; ++mi)
#pragma unroll
        for (int ni = 0; ni < 4; ++ni)
          acc[mi][ni] = __builtin_amdgcn_mfma_f32_16x16x32_bf16(af2[mi], bf2[ni], acc[mi][ni], 0, 0, 0);
    }
    __syncthreads();
  }

  const int rsub = (lane >> 4) * 4, csub = lane & 15;
#pragma unroll
  for (int ni = 0; ni < 4; ++ni) {
    const int n = n0 + wn + ni * 16 + csub;
    const float bv = bz[n];
#pragma unroll
    for (int mi = 0; mi < 4; ++mi) {
#pragma unroll
      for (int r = 0; r < 4; ++r) {
        const int m = m0 + wm + mi * 16 + rsub + r;
        float v = acc[mi][ni][r] + bv;
        const int t = tok[zb * M + m];
        const float s = scale[zb * M + m];
        atomicAdd(&outF[(size_t)t * N + n], v * s);
      }
    }
  }
}

extern "C" void kernel_launch(void* const* d_in, const int* in_sizes, int n_in,
                              void* d_out, int out_size, void* d_ws, size_t ws_size,
                              hipStream_t stream) {
  const float* x      = (const float*)d_in[0];
  const float* gate_w = (const float*)d_in[1];
  const float* gate_b = (const float*)d_in[2];
  const float* temp   = (const float*)d_in[3];
  const float* sw1    = (const float*)d_in[4];
  const float* sb1    = (const float*)d_in[5];
  const float* sw2    = (const float*)d_in[6];
  const float* sb2    = (const float*)d_in[7];
  const float* ew1    = (const float*)d_in[8];
  const float* eb1    = (const float*)d_in[9];
  const float* ew2    = (const float*)d_in[10];
  const float* eb2    = (const float*)d_in[11];
  float* out = (float*)d_out;

  char* ws = (char*)d_ws;
  size_t o = 0;
  auto take = [&](size_t bytes) { char* p = ws + o; o += (bytes + 255) & ~(size_t)255; return p; };
  unsigned short* x_bf = (unsigned short*)take((size_t)NTOK * DMODEL * 2);
  unsigned short* w1t  = (unsigned short*)take((size_t)DMODEL * DHID * 2);
  unsigned short* w2t  = (unsigned short*)take((size_t)DHID * DMODEL * 2);
  unsigned short* ew1t = (unsigned short*)take((size_t)NEXP * DMODEL * DHID * 2);
  unsigned short* ew2t = (unsigned short*)take((size_t)NEXP * DHID * DMODEL * 2);
  float* probs         = (float*)take((size_t)NEXP * NTOK * 4);
  int* tok             = (int*)take((size_t)NEXP * CAP * 4);
  float* scores        = (float*)take((size_t)NEXP * CAP * 4);
  int* eqbuf           = (int*)take((size_t)NEXP * NTOK * 4);
  unsigned short* atok = (unsigned short*)take((size_t)NEXP * CAP * DMODEL * 2);
  unsigned short* he   = (unsigned short*)take((size_t)NEXP * CAP * DHID * 2);
  unsigned short* hs   = (unsigned short*)take((size_t)NTOK * DHID * 2);

  // prep: bf16 conversions + weight transposes
  k_convert_bf16<<<4096, 256, 0, stream>>>(x, x_bf, NTOK * DMODEL / 4);
  k_trans_conv<<<dim3(DHID / 32, DMODEL / 32, 1), 256, 0, stream>>>(sw1, w1t, DMODEL, DHID);
  k_trans_conv<<<dim3(DMODEL / 32, DHID / 32, 1), 256, 0, stream>>>(sw2, w2t, DHID, DMODEL);
  k_trans_conv<<<dim3(DHID / 32, DMODEL / 32, NEXP), 256, 0, stream>>>(ew1, ew1t, DMODEL, DHID);
  k_trans_conv<<<dim3(DMODEL / 32, DHID / 32, NEXP), 256, 0, stream>>>(ew2, ew2t, DHID, DMODEL);

  // router + top-k + gather
  k_router<<<NTOK / 4, 256, 0, stream>>>(x, gate_w, gate_b, temp, probs);
  k_topk<<<NEXP, 256, 0, stream>>>(probs, tok, scores, eqbuf);
  k_gather<<<NEXP * CAP, 256, 0, stream>>>(x_bf, tok, atok);

  // shared FFN (256^2 two-phase ring-4 kernel)
  k_gemm_big<0><<<dim3(NTOK / 256, DHID / 256, 1), 512, 0, stream>>>(
      x_bf, w1t, sb1, nullptr, hs, NTOK, DHID, DMODEL);
  k_gemm_big<1><<<dim3(NTOK / 256, DMODEL / 256, 1), 512, 0, stream>>>(
      hs, w2t, sb2, out, nullptr, NTOK, DMODEL, DHID);

  // routed experts: FFN-1 on the big kernel; FFN-2 scatter on 128^2 (256 blocks)
  k_gemm_big<0><<<dim3(CAP / 256, DHID / 256, NEXP), 512, 0, stream>>>(
      atok, ew1t, eb1, nullptr, he, CAP, DHID, DMODEL);
  k_gemm_scatter<<<dim3(CAP / 128, DMODEL / 128, NEXP), 256, 0, stream>>>(
      he, ew2t, eb2, out, tok, scores, CAP, DMODEL, DHID);
}

// Round 7
// 700.798 us; speedup vs baseline: 1.3024x; 1.0921x over previous
//
#include <hip/hip_runtime.h>

#define NTOK 16384
#define DMODEL 1024
#define DHID 4096
#define NEXP 8
#define CAP 512

typedef __attribute__((ext_vector_type(8))) short bfrag_t;
typedef __attribute__((ext_vector_type(4))) float ffrag_t;

__device__ __forceinline__ unsigned short f2bf(float f) {
  unsigned u = __float_as_uint(f);
  u += 0x7FFFu + ((u >> 16) & 1u);
  return (unsigned short)(u >> 16);
}

// gelu(x) = 0.5x(1+tanh(u)) = x * sigmoid(2u), u = 0.79788456(x + 0.044715x^3)
// 2u = x*(1.5957691 + 0.071354814*x^2).  ~8 VALU ops (1 v_exp, 1 v_rcp) vs ~25 for tanhf.
__device__ __forceinline__ float gelu_fast(float x) {
  float t = x * x;
  float z = x * fmaf(0.071354814f, t, 1.5957691f);
  float e = __expf(-z);
  return x * __builtin_amdgcn_rcpf(1.0f + e);
}

// ---------------- convert f32 -> bf16 flat ----------------
__global__ void k_convert_bf16(const float* __restrict__ in, unsigned short* __restrict__ out, int n4) {
  int i = blockIdx.x * blockDim.x + threadIdx.x;
  int stride = gridDim.x * blockDim.x;
  for (; i < n4; i += stride) {
    float4 v = ((const float4*)in)[i];
    ushort4 o;
    o.x = f2bf(v.x); o.y = f2bf(v.y); o.z = f2bf(v.z); o.w = f2bf(v.w);
    ((ushort4*)out)[i] = o;
  }
}

// ------------- transpose+convert: in [K,N] f32 -> out [N,K] bf16, batch z -------------
__global__ void k_trans_conv(const float* __restrict__ in, unsigned short* __restrict__ out, int K, int N) {
  const size_t zb = blockIdx.z;
  in  += zb * (size_t)K * N;
  out += zb * (size_t)N * K;
  __shared__ float tile[32][33];
  const int n0 = blockIdx.x * 32, k0 = blockIdx.y * 32;
  const int tx = threadIdx.x & 31, ty = threadIdx.x >> 5;
#pragma unroll
  for (int i = 0; i < 4; ++i) {
    int k = ty + i * 8;
    tile[k][tx] = in[(size_t)(k0 + k) * N + n0 + tx];
  }
  __syncthreads();
#pragma unroll
  for (int i = 0; i < 4; ++i) {
    int n = ty + i * 8;
    out[(size_t)(n0 + n) * K + k0 + tx] = f2bf(tile[tx][n]);
  }
}

// ---------------- router: probs[e][t] ----------------
__global__ __launch_bounds__(256) void k_router(const float* __restrict__ x, const float* __restrict__ gw,
                                                const float* __restrict__ gb, const float* __restrict__ temp,
                                                float* __restrict__ probs) {
  __shared__ float gws[DMODEL * NEXP];
  for (int i = threadIdx.x; i < DMODEL * NEXP; i += 256) gws[i] = gw[i];
  __syncthreads();
  const int wave = threadIdx.x >> 6, lane = threadIdx.x & 63;
  const int t = blockIdx.x * 4 + wave;
  const float* xr = x + (size_t)t * DMODEL;
  float acc[NEXP];
#pragma unroll
  for (int e = 0; e < NEXP; ++e) acc[e] = 0.f;
  for (int d = lane; d < DMODEL; d += 64) {
    float xv = xr[d];
#pragma unroll
    for (int e = 0; e < NEXP; ++e) acc[e] += xv * gws[d * NEXP + e];
  }
#pragma unroll
  for (int off = 32; off >= 1; off >>= 1) {
#pragma unroll
    for (int e = 0; e < NEXP; ++e) acc[e] += __shfl_xor(acc[e], off);
  }
  if (lane == 0) {
    float st = fmaxf(temp[0], 0.1f);
    float m = -1e30f;
#pragma unroll
    for (int e = 0; e < NEXP; ++e) { acc[e] = (acc[e] + gb[e]) / st; m = fmaxf(m, acc[e]); }
    float s = 0.f;
#pragma unroll
    for (int e = 0; e < NEXP; ++e) { acc[e] = expf(acc[e] - m); s += acc[e]; }
    float inv = 1.f / s;
#pragma unroll
    for (int e = 0; e < NEXP; ++e) probs[(size_t)e * NTOK + t] = acc[e] * inv;
  }
}

// ---------------- exact top-512 per expert (radix select, tie -> lowest index) ----------------
__global__ __launch_bounds__(256) void k_topk(const float* __restrict__ probs, int* __restrict__ tok,
                                              float* __restrict__ scores, int* __restrict__ eqbuf) {
  const int e = blockIdx.x;
  const float* p = probs + (size_t)e * NTOK;
  int* eq = eqbuf + (size_t)e * NTOK;
  __shared__ int hist[256];
  __shared__ unsigned sh_pref;
  __shared__ int sh_k, sh_gt, sh_eq, sh_cnt;
  const int tid = threadIdx.x;
  if (tid == 0) { sh_pref = 0u; sh_k = CAP; }
  __syncthreads();
  for (int pass = 3; pass >= 0; --pass) {
    hist[tid] = 0;
    __syncthreads();
    const unsigned pref = sh_pref;
    const int shift = pass * 8;
    for (int t = tid; t < NTOK; t += 256) {
      unsigned key = __float_as_uint(p[t]);
      bool cand = (pass == 3) || ((key >> (shift + 8)) == pref);
      if (cand) atomicAdd(&hist[(key >> shift) & 255], 1);
    }
    __syncthreads();
    if (tid == 0) {
      int k = sh_k;
      int d = 255;
      while (hist[d] < k) { k -= hist[d]; --d; }
      sh_k = k;
      sh_pref = (pref << 8) | (unsigned)d;
    }
    __syncthreads();
  }
  const unsigned Kstar = sh_pref;
  const int need_eq = sh_k;
  if (tid == 0) { sh_gt = 0; sh_eq = 0; }
  __syncthreads();
  for (int t = tid; t < NTOK; t += 256) {
    unsigned key = __float_as_uint(p[t]);
    if (key > Kstar) {
      int pos = atomicAdd(&sh_gt, 1);
      tok[e * CAP + pos] = t;
      scores[e * CAP + pos] = p[t];
    } else if (key == Kstar) {
      int q = atomicAdd(&sh_eq, 1);
      eq[q] = t;
    }
  }
  __syncthreads();
  const int cg = sh_gt, ce = sh_eq;
  if (ce <= need_eq) {
    for (int j = tid; j < ce; j += 256) {
      tok[e * CAP + cg + j] = eq[j];
      scores[e * CAP + cg + j] = p[eq[j]];
    }
  } else {
    int lo = 0, hi = NTOK - 1;
    while (lo < hi) {
      int mid = (lo + hi) >> 1;
      if (tid == 0) sh_cnt = 0;
      __syncthreads();
      for (int j = tid; j < ce; j += 256)
        if (eq[j] <= mid) atomicAdd(&sh_cnt, 1);
      __syncthreads();
      if (sh_cnt >= need_eq) hi = mid; else lo = mid + 1;
      __syncthreads();
    }
    if (tid == 0) sh_cnt = 0;
    __syncthreads();
    for (int j = tid; j < ce; j += 256) {
      if (eq[j] <= lo) {
        int pos = cg + atomicAdd(&sh_cnt, 1);
        tok[e * CAP + pos] = eq[j];
        scores[e * CAP + pos] = p[eq[j]];
      }
    }
  }
}

// ---------------- gather selected tokens (bf16 rows) ----------------
__global__ void k_gather(const unsigned short* __restrict__ xb, const int* __restrict__ tok,
                         unsigned short* __restrict__ atok) {
  const int row = blockIdx.x;
  const int t = tok[row];
  const uint2* src = (const uint2*)(xb + (size_t)t * DMODEL);
  uint2* dst = (uint2*)(atok + (size_t)row * DMODEL);
  dst[threadIdx.x] = src[threadIdx.x];
}

// =====================================================================================
// m97-structure GEMM: 128x128 tile, BK=64, 4 waves (2Mx2N), SINGLE 32KB LDS buffer,
// plain __syncthreads (the vmcnt-drain is absorbed by 4 blocks/CU co-residency — m114).
// __launch_bounds__(256, 4) => 4 waves/EU = 4 blocks/CU (LDS 4x32KB = 128KB <= 160KB).
// Staging: global_load_lds 16B, LDS granule-XOR swizzle slot = g ^ (row&7) (2-way bank
// aliasing on reads = free, m136). Source pre-permuted, LDS dest linear.
// MODE 0: outB[(zb*M+m)*N+n] = bf16(gelu(v))  via LDS-bounce (full 256B-row stores)
// MODE 1: outF[m*N+n] = v
// MODE 2: atomicAdd(outF[tok[zb*M+m]*N+n], v*scale[zb*M+m]); bias added only when kc==0.
//         K-split: blockIdx.z = zb*ksplit + kc; loop Kloop cols at offset kc*Kloop.
// =====================================================================================
template <int MODE>
__global__ __launch_bounds__(256, 4) void k_gemm(
    const unsigned short* __restrict__ A, const unsigned short* __restrict__ Bt,
    const float* __restrict__ bias, float* __restrict__ outF, unsigned short* __restrict__ outB,
    const int* __restrict__ tok, const float* __restrict__ scale,
    int M, int N, int Kloop, int LDK, int ksplit) {
  const int zb = blockIdx.z / ksplit;
  const int kc = blockIdx.z % ksplit;
  A += (size_t)zb * M * LDK + (size_t)kc * Kloop;
  Bt += (size_t)zb * N * LDK + (size_t)kc * Kloop;
  const float* bz = bias + (size_t)zb * N;

  // XCD slab swizzle
  const int gx = gridDim.x, gy = gridDim.y;
  const int nwg = gx * gy;
  const int id = blockIdx.x + blockIdx.y * gx;
  int bx, by;
  if ((gx & 7) == 0) {
    const int x = id & 7, c = id >> 3, H = gx >> 3;
    bx = x * H + (c % H);
    by = c / H;
  } else if ((nwg & 7) == 0) {
    const int q = nwg >> 3;
    const int sw = (id & 7) * q + (id >> 3);
    bx = sw % gx;
    by = sw / gx;
  } else {
    bx = blockIdx.x;
    by = blockIdx.y;
  }
  const int m0 = bx * 128, n0 = by * 128;

  const int tid = threadIdx.x, wave = tid >> 6, lane = tid & 63;
  const int wm = (wave >> 1) * 64, wn = (wave & 1) * 64;

  __shared__ alignas(16) unsigned short sh[128 * 128];  // 32KB; As = sh, Bs = sh+8192
  unsigned short* As = sh;
  unsigned short* Bs = sh + 128 * 64;

  ffrag_t acc[4][4];
#pragma unroll
  for (int i = 0; i < 4; ++i)
#pragma unroll
    for (int j = 0; j < 4; ++j)
#pragma unroll
      for (int r = 0; r < 4; ++r) acc[i][j][r] = 0.f;

  // staging geometry (verified in R1): thread slot L = it*256+tid -> row = L>>3,
  // LDS slot gs = L&7 holds logical granule g = gs ^ (row&7); LDS dest linear L*16.
  int rr[4], gg[4], lb[4];
#pragma unroll
  for (int it = 0; it < 4; ++it) {
    int L = it * 256 + tid;
    rr[it] = L >> 3;
    gg[it] = (L & 7) ^ (rr[it] & 7);
    lb[it] = (it * 256 + wave * 64) * 16;  // wave-uniform byte base; HW adds lane*16
  }

  for (int kt = 0; kt < Kloop; kt += 64) {
#pragma unroll
    for (int it = 0; it < 4; ++it) {
      const unsigned short* sA = A + (size_t)(m0 + rr[it]) * LDK + kt + gg[it] * 8;
      const unsigned short* sB = Bt + (size_t)(n0 + rr[it]) * LDK + kt + gg[it] * 8;
      __builtin_amdgcn_global_load_lds((const __attribute__((address_space(1))) unsigned int*)sA,
                                       (__attribute__((address_space(3))) unsigned int*)((char*)As + lb[it]),
                                       16, 0, 0);
      __builtin_amdgcn_global_load_lds((const __attribute__((address_space(1))) unsigned int*)sB,
                                       (__attribute__((address_space(3))) unsigned int*)((char*)Bs + lb[it]),
                                       16, 0, 0);
    }
    __syncthreads();
#pragma unroll
    for (int kk = 0; kk < 2; ++kk) {
      bfrag_t af[4], bf[4];
      const int gl = kk * 4 + (lane >> 4);
#pragma unroll
      for (int mi = 0; mi < 4; ++mi) {
        int r = wm + mi * 16 + (lane & 15);
        af[mi] = *(const bfrag_t*)&As[r * 64 + ((gl ^ (r & 7)) * 8)];
      }
#pragma unroll
      for (int ni = 0; ni < 4; ++ni) {
        int r = wn + ni * 16 + (lane & 15);
        bf[ni] = *(const bfrag_t*)&Bs[r * 64 + ((gl ^ (r & 7)) * 8)];
      }
#pragma unroll
      for (int mi = 0; mi < 4; ++mi)
#pragma unroll
        for (int ni = 0; ni < 4; ++ni)
          acc[mi][ni] = __builtin_amdgcn_mfma_f32_16x16x32_bf16(af[mi], bf[ni], acc[mi][ni], 0, 0, 0);
    }
    __syncthreads();
  }

  // epilogue: C/D layout col = lane&15, row = (lane>>4)*4 + reg
  const int rsub = (lane >> 4) * 4, cs = lane & 15;
  if (MODE == 0) {
    // LDS-bounce: stage bf16 tile (exactly 32KB) then store full 256B rows
    float bv[4];
#pragma unroll
    for (int ni = 0; ni < 4; ++ni) bv[ni] = bz[n0 + wn + ni * 16 + cs];
#pragma unroll
    for (int mi = 0; mi < 4; ++mi)
#pragma unroll
      for (int ni = 0; ni < 4; ++ni)
#pragma unroll
        for (int r = 0; r < 4; ++r) {
          float v = acc[mi][ni][r] + bv[ni];
          sh[(wm + mi * 16 + rsub + r) * 128 + (wn + ni * 16 + cs)] = f2bf(gelu_fast(v));
        }
    __syncthreads();
    const int seg = tid & 15, rw = tid >> 4;
#pragma unroll
    for (int rep = 0; rep < 8; ++rep) {
      const int row = rep * 16 + rw;
      uint4 v = *(const uint4*)&sh[row * 128 + seg * 8];
      *(uint4*)&outB[((size_t)zb * M + m0 + row) * N + n0 + seg * 8] = v;
    }
  } else if (MODE == 1) {
#pragma unroll
    for (int ni = 0; ni < 4; ++ni) {
      const int n = n0 + wn + ni * 16 + cs;
      const float bv = bz[n];
#pragma unroll
      for (int mi = 0; mi < 4; ++mi)
#pragma unroll
        for (int r = 0; r < 4; ++r) {
          const int m = m0 + wm + mi * 16 + rsub + r;
          outF[(size_t)m * N + n] = acc[mi][ni][r] + bv;
        }
    }
  } else {
#pragma unroll
    for (int ni = 0; ni < 4; ++ni) {
      const int n = n0 + wn + ni * 16 + cs;
      const float bv = (kc == 0) ? bz[n] : 0.f;
#pragma unroll
      for (int mi = 0; mi < 4; ++mi)
#pragma unroll
        for (int r = 0; r < 4; ++r) {
          const int m = m0 + wm + mi * 16 + rsub + r;
          const int t = tok[zb * M + m];
          const float s = scale[zb * M + m];
          atomicAdd(&outF[(size_t)t * N + n], (acc[mi][ni][r] + bv) * s);
        }
    }
  }
}

extern "C" void kernel_launch(void* const* d_in, const int* in_sizes, int n_in,
                              void* d_out, int out_size, void* d_ws, size_t ws_size,
                              hipStream_t stream) {
  const float* x      = (const float*)d_in[0];
  const float* gate_w = (const float*)d_in[1];
  const float* gate_b = (const float*)d_in[2];
  const float* temp   = (const float*)d_in[3];
  const float* sw1    = (const float*)d_in[4];
  const float* sb1    = (const float*)d_in[5];
  const float* sw2    = (const float*)d_in[6];
  const float* sb2    = (const float*)d_in[7];
  const float* ew1    = (const float*)d_in[8];
  const float* eb1    = (const float*)d_in[9];
  const float* ew2    = (const float*)d_in[10];
  const float* eb2    = (const float*)d_in[11];
  float* out = (float*)d_out;

  char* ws = (char*)d_ws;
  size_t o = 0;
  auto take = [&](size_t bytes) { char* p = ws + o; o += (bytes + 255) & ~(size_t)255; return p; };
  unsigned short* x_bf = (unsigned short*)take((size_t)NTOK * DMODEL * 2);
  unsigned short* w1t  = (unsigned short*)take((size_t)DMODEL * DHID * 2);
  unsigned short* w2t  = (unsigned short*)take((size_t)DHID * DMODEL * 2);
  unsigned short* ew1t = (unsigned short*)take((size_t)NEXP * DMODEL * DHID * 2);
  unsigned short* ew2t = (unsigned short*)take((size_t)NEXP * DHID * DMODEL * 2);
  float* probs         = (float*)take((size_t)NEXP * NTOK * 4);
  int* tok             = (int*)take((size_t)NEXP * CAP * 4);
  float* scores        = (float*)take((size_t)NEXP * CAP * 4);
  int* eqbuf           = (int*)take((size_t)NEXP * NTOK * 4);
  unsigned short* atok = (unsigned short*)take((size_t)NEXP * CAP * DMODEL * 2);
  unsigned short* he   = (unsigned short*)take((size_t)NEXP * CAP * DHID * 2);
  unsigned short* hs   = (unsigned short*)take((size_t)NTOK * DHID * 2);

  // prep: bf16 conversions + weight transposes
  k_convert_bf16<<<4096, 256, 0, stream>>>(x, x_bf, NTOK * DMODEL / 4);
  k_trans_conv<<<dim3(DHID / 32, DMODEL / 32, 1), 256, 0, stream>>>(sw1, w1t, DMODEL, DHID);
  k_trans_conv<<<dim3(DMODEL / 32, DHID / 32, 1), 256, 0, stream>>>(sw2, w2t, DHID, DMODEL);
  k_trans_conv<<<dim3(DHID / 32, DMODEL / 32, NEXP), 256, 0, stream>>>(ew1, ew1t, DMODEL, DHID);
  k_trans_conv<<<dim3(DMODEL / 32, DHID / 32, NEXP), 256, 0, stream>>>(ew2, ew2t, DHID, DMODEL);

  // router + top-k + gather
  k_router<<<NTOK / 4, 256, 0, stream>>>(x, gate_w, gate_b, temp, probs);
  k_topk<<<NEXP, 256, 0, stream>>>(probs, tok, scores, eqbuf);
  k_gather<<<NEXP * CAP, 256, 0, stream>>>(x_bf, tok, atok);

  // shared FFN
  k_gemm<0><<<dim3(128, 32, 1), 256, 0, stream>>>(
      x_bf, w1t, sb1, nullptr, hs, nullptr, nullptr, NTOK, DHID, DMODEL, DMODEL, 1);
  k_gemm<1><<<dim3(128, 8, 1), 256, 0, stream>>>(
      hs, w2t, sb2, out, nullptr, nullptr, nullptr, NTOK, DMODEL, DHID, DHID, 1);

  // routed experts: FFN-1 batched over experts; FFN-2 scatter with K-split x4
  k_gemm<0><<<dim3(4, 32, NEXP), 256, 0, stream>>>(
      atok, ew1t, eb1, nullptr, he, nullptr, nullptr, CAP, DHID, DMODEL, DMODEL, 1);
  k_gemm<2><<<dim3(4, 8, NEXP * 4), 256, 0, stream>>>(
      he, ew2t, eb2, out, nullptr, tok, scores, CAP, DMODEL, DHID / 4, DHID, 4);
}